// Round 2
// baseline (4402.207 us; speedup 1.0000x reference)
//
#include <hip/hip_runtime.h>
#include <hip/hip_bf16.h>

typedef unsigned short u16;

#define NN 20000
#define HH 64
#define EMBD 300
#define EE 160000
#define BB 4096

// f32 param block offsets (in floats) inside workspace (after 16-float header)
#define OFF_PROJW 0
#define OFF_PROJB 19200
#define OFF_MSGW  19264
#define OFF_MSGB  27456
#define OFF_WIH   27584
#define OFF_WHH   52160
#define OFF_BIH   76736
#define OFF_BHH   77120
#define OFF_CW1   77504
#define OFF_CB1   79552
#define OFF_CW2   79568
#define OFF_CB2   79584
#define PARAM_SZ  81920

__device__ __forceinline__ float b2f(u16 u) {
    union { unsigned int i; float f; } v; v.i = ((unsigned int)u) << 16; return v.f;
}
__device__ __forceinline__ u16 f2b(float f) {
    union { float f; unsigned int u; } v; v.f = f;
    unsigned int u = v.u;
    return (u16)((u + 0x7FFFu + ((u >> 16) & 1u)) >> 16);   // RNE
}
// dtype-flexible load/store: isbf=1 -> bf16 array, isbf=0 -> f32 array
__device__ __forceinline__ float ldf(const void* p, long long i, int isbf) {
    return isbf ? b2f(((const u16*)p)[i]) : ((const float*)p)[i];
}
__device__ __forceinline__ void stf(void* p, long long i, int isbf, float v) {
    if (isbf) ((u16*)p)[i] = f2b(v);
    else      ((float*)p)[i] = v;
}

// ---------------- dtype sniffer ----------------
// bf16 array: even-index u16s are bf16 values ~N(0,0.05^2) -> exponent field in
// [~113,126] for nearly all. f32 array: even-index u16s are low mantissa bits
// (uniform noise) -> ~7% land in that range. Threshold at 48/64.
__global__ void sniff_kernel(const u16* probe, int* flag)
{
    if (threadIdx.x == 0 && blockIdx.x == 0) {
        int good = 0;
        for (int i = 0; i < 128; i += 2) {
            unsigned int e = (probe[i] >> 7) & 0xFF;   // exponent field
            if (e >= 105 && e <= 127) good++;
        }
        *flag = (good >= 48) ? 1 : 0;
    }
}

// ---------------- param convert (-> f32 block) ----------------
__global__ __launch_bounds__(256) void conv_kernel(
    const void* projW, const void* projb, const void* msgW, const void* msgb,
    const void* wih, const void* whh, const void* bih, const void* bhh,
    const void* cw1, const void* cb1, const void* cw2, const void* cb2,
    float* P, const int* flag)
{
    int isbf = *flag;
    int i = blockIdx.x * 256 + threadIdx.x;
    if (i < 19200) P[OFF_PROJW + i] = ldf(projW, i, isbf);
    if (i < 64)    P[OFF_PROJB + i] = ldf(projb, i, isbf);
    if (i < 8192)  P[OFF_MSGW + i]  = ldf(msgW, i, isbf);
    if (i < 128)   P[OFF_MSGB + i]  = ldf(msgb, i, isbf);
    if (i < 24576) { P[OFF_WIH + i] = ldf(wih, i, isbf); P[OFF_WHH + i] = ldf(whh, i, isbf); }
    if (i < 384)   { P[OFF_BIH + i] = ldf(bih, i, isbf); P[OFF_BHH + i] = ldf(bhh, i, isbf); }
    if (i < 2048)  P[OFF_CW1 + i] = ldf(cw1, i, isbf);
    if (i < 16)    { P[OFF_CB1 + i] = ldf(cb1, i, isbf); P[OFF_CW2 + i] = ldf(cw2, i, isbf); }
    if (i == 0)    P[OFF_CB2] = ldf(cb2, 0, isbf);
}

// ---------------- CSR build ----------------
__global__ __launch_bounds__(256) void hist_kernel(const int* adj0, const int* adj1, int* off)
{
    int e = blockIdx.x * 256 + threadIdx.x;
    if (e >= 2 * EE) return;
    int b = e / EE, le = e - b * EE;
    const int* adj = b ? adj1 : adj0;
    int tgt = adj[2 * le + 1];
    atomicAdd(&off[b * (NN + 1) + tgt + 1], 1);
}

__global__ __launch_bounds__(1024) void scan_kernel(int* off, int* cursor)
{
    const int NB = 1024;
    int b = blockIdx.x;
    int* o = off + (size_t)b * (NN + 1);
    int* cur = cursor + (size_t)b * NN;
    __shared__ int buf[NB];
    __shared__ int sbase;
    int tid = threadIdx.x;
    if (tid == 0) sbase = 0;
    __syncthreads();
    for (int start = 0; start < NN; start += NB) {
        int i = start + tid;
        int v = (i < NN) ? o[i + 1] : 0;
        buf[tid] = v;
        __syncthreads();
        for (int s = 1; s < NB; s <<= 1) {
            int t = (tid >= s) ? buf[tid - s] : 0;
            __syncthreads();
            buf[tid] += t;
            __syncthreads();
        }
        int incl = buf[tid];
        int excl = incl - v;
        int base = sbase;
        if (i < NN) { o[i] = base + excl; cur[i] = base + excl; }
        __syncthreads();
        if (tid == NB - 1) sbase = base + incl;
        __syncthreads();
    }
    if (tid == 0) o[NN] = sbase;
}

__global__ __launch_bounds__(256) void scatter_kernel(const int* adj0, const int* adj1,
                                                      int* cursor, int* esrc)
{
    int e = blockIdx.x * 256 + threadIdx.x;
    if (e >= 2 * EE) return;
    int b = e / EE, le = e - b * EE;
    const int* adj = b ? adj1 : adj0;
    int src = adj[2 * le + 0];
    int tgt = adj[2 * le + 1];
    int pos = atomicAdd(&cursor[b * NN + tgt], 1);
    esrc[(size_t)b * EE + pos] = src;
}

// ---------------- embedding gather + projection ----------------
__global__ __launch_bounds__(256) void proj_kernel(const void* emb, const int* ind0, const int* ind1,
                                                   const float* P, float* h, const int* flag)
{
    __shared__ float s_emb[4][EMBD];
    __shared__ float s_W[64 * 64];
    int isbf = *flag;
    int g = threadIdx.x >> 6, lane = threadIdx.x & 63;
    int node = blockIdx.x * 4 + g;          // grid = 10000 -> node < 40000 exact
    int b = node >= NN;
    int ln = node - b * NN;
    int idx = b ? ind1[ln] : ind0[ln];
    long long rowoff = (long long)idx * EMBD;
    for (int k = lane; k < EMBD; k += 64) s_emb[g][k] = ldf(emb, rowoff + k, isbf);
    float acc = P[OFF_PROJB + lane];
    for (int k0 = 0; k0 < EMBD; k0 += 64) {
        int kl = (EMBD - k0) < 64 ? (EMBD - k0) : 64;
        __syncthreads();
        for (int t = threadIdx.x; t < kl * 64; t += 256)
            s_W[t] = P[OFF_PROJW + k0 * 64 + t];
        __syncthreads();
        for (int kk = 0; kk < kl; ++kk)
            acc += s_emb[g][k0 + kk] * s_W[kk * 64 + lane];
    }
    h[(size_t)node * 64 + lane] = acc;
}

// ---------------- neighbor gather-sum (S = segment_sum h[src]) ----------------
__global__ __launch_bounds__(256) void gather_kernel(const float* h, const int* off,
                                                     const int* esrc, float* S)
{
    int g = threadIdx.x >> 6, lane = threadIdx.x & 63;
    int node = blockIdx.x * 4 + g;
    int b = node >= NN;
    int ln = node - b * NN;
    const int* o = off + (size_t)b * (NN + 1);
    int s0 = o[ln], s1 = o[ln + 1];
    const int* es = esrc + (size_t)b * EE;
    const float* hb = h + (size_t)b * NN * 64;
    float acc = 0.f;
    for (int i = s0; i < s1; ++i) {
        int src = es[i];
        acc += hb[(size_t)src * 64 + lane];
    }
    S[(size_t)node * 64 + lane] = acc;
}

// ---------------- fused message-matmul + GRU cell ----------------
__global__ __launch_bounds__(256) void gru_kernel(const float* S, float* h, const int* off,
                                                  const float* P, int l)
{
    __shared__ float s_msgW[64 * 64];
    __shared__ __align__(16) float s_x[4][64];
    __shared__ __align__(16) float s_h[4][64];
    __shared__ __align__(16) float s_s[4][64];
    int g = threadIdx.x >> 6, lane = threadIdx.x & 63;
    int node = blockIdx.x * 4 + g;
    int b = node >= NN;
    int ln = node - b * NN;

    for (int t = threadIdx.x; t < 4096; t += 256)
        s_msgW[t] = P[OFF_MSGW + l * 4096 + t];
    s_s[g][lane] = S[(size_t)node * 64 + lane];
    float hval = h[(size_t)node * 64 + lane];
    s_h[g][lane] = hval;
    const int* o = off + (size_t)b * (NN + 1);
    int deg = o[ln + 1] - o[ln];
    __syncthreads();

    float acc = (float)deg * P[OFF_MSGB + l * 64 + lane];
    #pragma unroll 8
    for (int k = 0; k < 64; ++k) acc += s_s[g][k] * s_msgW[k * 64 + lane];
    s_x[g][lane] = acc;
    __syncthreads();

    const float* Wih = P + OFF_WIH + l * 12288;
    const float* Whh = P + OFF_WHH + l * 12288;
    float ir = P[OFF_BIH + l * 192 + lane];
    float iz = P[OFF_BIH + l * 192 + 64 + lane];
    float in_ = P[OFF_BIH + l * 192 + 128 + lane];
    float hr = P[OFF_BHH + l * 192 + lane];
    float hz = P[OFF_BHH + l * 192 + 64 + lane];
    float hn = P[OFF_BHH + l * 192 + 128 + lane];

    const float4* wr_i = (const float4*)(Wih + (size_t)lane * 64);
    const float4* wz_i = (const float4*)(Wih + (size_t)(64 + lane) * 64);
    const float4* wn_i = (const float4*)(Wih + (size_t)(128 + lane) * 64);
    const float4* wr_h = (const float4*)(Whh + (size_t)lane * 64);
    const float4* wz_h = (const float4*)(Whh + (size_t)(64 + lane) * 64);
    const float4* wn_h = (const float4*)(Whh + (size_t)(128 + lane) * 64);
    const float4* xv4 = (const float4*)s_x[g];
    const float4* hv4 = (const float4*)s_h[g];
    #pragma unroll
    for (int k4 = 0; k4 < 16; ++k4) {
        float4 x = xv4[k4], hh = hv4[k4];
        float4 w;
        w = wr_i[k4]; ir += x.x * w.x + x.y * w.y + x.z * w.z + x.w * w.w;
        w = wz_i[k4]; iz += x.x * w.x + x.y * w.y + x.z * w.z + x.w * w.w;
        w = wn_i[k4]; in_ += x.x * w.x + x.y * w.y + x.z * w.z + x.w * w.w;
        w = wr_h[k4]; hr += hh.x * w.x + hh.y * w.y + hh.z * w.z + hh.w * w.w;
        w = wz_h[k4]; hz += hh.x * w.x + hh.y * w.y + hh.z * w.z + hh.w * w.w;
        w = wn_h[k4]; hn += hh.x * w.x + hh.y * w.y + hh.z * w.z + hh.w * w.w;
    }
    float r = 1.f / (1.f + __expf(-(ir + hr)));
    float z = 1.f / (1.f + __expf(-(iz + hz)));
    float n = tanhf(in_ + r * hn);
    h[(size_t)node * 64 + lane] = (1.f - z) * n + z * hval;
}

// ---------------- classifier + partial loss ----------------
__global__ __launch_bounds__(256) void cls_kernel(const float* h, const int* p0, const int* p1,
                                                  const int* labels, const float* P,
                                                  void* out, float* partial, const int* flag)
{
    int isbf = *flag;
    int r = blockIdx.x * 256 + threadIdx.x;   // 16 blocks x 256 = 4096 exact
    int n0 = p0[r], n1 = p1[r];
    const float* h0 = h + (size_t)n0 * 64;
    const float* h1 = h + (size_t)(NN + n1) * 64;
    float feat[128];
    #pragma unroll
    for (int k = 0; k < 64; ++k) { feat[k] = h0[k]; feat[64 + k] = h1[k]; }
    float zacc = P[OFF_CB2];
    #pragma unroll
    for (int t = 0; t < 16; ++t) {
        float a = P[OFF_CB1 + t];
        for (int k = 0; k < 128; ++k) a += feat[k] * P[OFF_CW1 + k * 16 + t];
        a = fmaxf(a, 0.f);
        zacc += a * P[OFF_CW2 + t];
    }
    float p = 1.f / (1.f + expf(-zacc));
    stf(out, r, isbf, p);
    float y = (float)labels[r];
    const float eps = 1e-7f;
    float pc  = fminf(fmaxf(p, eps), 1.f);
    float pc1 = fminf(fmaxf(1.f - p, eps), 1.f);
    float term = y * logf(pc) + (1.f - y) * logf(pc1);
    __shared__ float red[256];
    red[threadIdx.x] = term;
    __syncthreads();
    for (int s = 128; s > 0; s >>= 1) {
        if (threadIdx.x < s) red[threadIdx.x] += red[threadIdx.x + s];
        __syncthreads();
    }
    if (threadIdx.x == 0) partial[blockIdx.x] = red[0];
}

__global__ void loss_kernel(const float* partial, void* out, const int* flag)
{
    if (threadIdx.x == 0 && blockIdx.x == 0) {
        float s = 0.f;
        for (int i = 0; i < 16; ++i) s += partial[i];
        stf(out, BB, *flag, -s / (float)BB);
    }
}

extern "C" void kernel_launch(void* const* d_in, const int* in_sizes, int n_in,
                              void* d_out, int out_size, void* d_ws, size_t ws_size,
                              hipStream_t stream)
{
    const int* emb_ind0 = (const int*)d_in[0];
    const int* emb_ind1 = (const int*)d_in[1];
    const int* adj0     = (const int*)d_in[2];
    const int* adj1     = (const int*)d_in[3];
    const int* prop0    = (const int*)d_in[4];
    const int* prop1    = (const int*)d_in[5];
    const int* labels   = (const int*)d_in[6];
    const void* emb     = d_in[7];
    const void* projW   = d_in[8];
    const void* projb   = d_in[9];
    const void* msgW    = d_in[10];
    const void* msgb    = d_in[11];
    const void* wih     = d_in[12];
    const void* whh     = d_in[13];
    const void* bihp    = d_in[14];
    const void* bhhp    = d_in[15];
    const void* cw1     = d_in[16];
    const void* cb1     = d_in[17];
    const void* cw2     = d_in[18];
    const void* cb2     = d_in[19];

    int* flag = (int*)d_ws;                 // 16-float header; flag in slot 0
    float* P = (float*)d_ws + 16;
    float* h = P + PARAM_SZ;
    float* S = h + 2 * NN * HH;
    float* partial = S + 2 * NN * HH;
    int* ioff   = (int*)(partial + 64);
    int* cursor = ioff + 2 * (NN + 1) + 62;
    int* esrc   = cursor + 2 * NN;

    hipMemsetAsync(ioff, 0, 2 * (NN + 1) * sizeof(int), stream);

    sniff_kernel<<<1, 64, 0, stream>>>((const u16*)projW, flag);
    conv_kernel<<<96, 256, 0, stream>>>(projW, projb, msgW, msgb, wih, whh, bihp, bhhp,
                                        cw1, cb1, cw2, cb2, P, flag);
    hist_kernel<<<(2 * EE) / 256, 256, 0, stream>>>(adj0, adj1, ioff);
    scan_kernel<<<2, 1024, 0, stream>>>(ioff, cursor);
    scatter_kernel<<<(2 * EE) / 256, 256, 0, stream>>>(adj0, adj1, cursor, esrc);
    proj_kernel<<<(2 * NN) / 4, 256, 0, stream>>>(emb, emb_ind0, emb_ind1, P, h, flag);

    for (int l = 0; l < 2; ++l) {
        for (int t = 0; t < 3; ++t) {
            gather_kernel<<<(2 * NN) / 4, 256, 0, stream>>>(h, ioff, esrc, S);
            gru_kernel<<<(2 * NN) / 4, 256, 0, stream>>>(S, h, ioff, P, l);
        }
    }

    cls_kernel<<<BB / 256, 256, 0, stream>>>(h, prop0, prop1, labels, P, d_out, partial, flag);
    loss_kernel<<<1, 64, 0, stream>>>(partial, d_out, flag);
}

// Round 3
// 1100.670 us; speedup vs baseline: 3.9996x; 3.9996x over previous
//
#include <hip/hip_runtime.h>
#include <hip/hip_bf16.h>

typedef unsigned short u16;
typedef __attribute__((ext_vector_type(8))) short s16x8;   // 8 bf16 (4 VGPRs) MFMA A/B frag
typedef __attribute__((ext_vector_type(4))) float f32x4;   // MFMA C/D frag

#define NN 20000
#define HH 64
#define EMBD 300
#define EE 160000
#define BB 4096

// f32 param block offsets (floats) in workspace (after 16-float header)
#define OFF_PROJW 0
#define OFF_PROJB 19200
#define OFF_MSGB  19264
#define OFF_BIH   19392
#define OFF_BHH   19776
#define OFF_CW1   20160
#define OFF_CB1   22208
#define OFF_CW2   22224
#define OFF_CB2   22240
#define PARAM_SZ  22272

// bf16 weight block offsets (u16 units): Wih[l][192][64] | Whh[l][192][64] | msgWT[l][64][64]
#define PB_WIH 0
#define PB_WHH 24576
#define PB_WMT 49152
#define PB_SZ  57344

// LDS weight offsets (u16 units)
#define WIH_S 0
#define WHH_S 12288
#define WMT_S 24576

__device__ __forceinline__ float b2f(u16 u) {
    union { unsigned int i; float f; } v; v.i = ((unsigned int)u) << 16; return v.f;
}
__device__ __forceinline__ u16 f2b(float f) {
    union { float f; unsigned int u; } v; v.f = f;
    unsigned int u = v.u;
    return (u16)((u + 0x7FFFu + ((u >> 16) & 1u)) >> 16);   // RNE
}
__device__ __forceinline__ float ldf(const void* p, long long i, int isbf) {
    return isbf ? b2f(((const u16*)p)[i]) : ((const float*)p)[i];
}
__device__ __forceinline__ u16 ldb(const void* p, long long i, int isbf) {
    return isbf ? ((const u16*)p)[i] : f2b(((const float*)p)[i]);
}
__device__ __forceinline__ void stf(void* p, long long i, int isbf, float v) {
    if (isbf) ((u16*)p)[i] = f2b(v);
    else      ((float*)p)[i] = v;
}

// ---------------- dtype sniffer (bf16 vs f32 input world) ----------------
__global__ void sniff_kernel(const u16* probe, int* flag)
{
    if (threadIdx.x == 0 && blockIdx.x == 0) {
        int good = 0;
        for (int i = 0; i < 128; i += 2) {
            unsigned int e = (probe[i] >> 7) & 0xFF;
            if (e >= 105 && e <= 127) good++;
        }
        *flag = (good >= 48) ? 1 : 0;
    }
}

// ---------------- param convert ----------------
__global__ __launch_bounds__(256) void conv_kernel(
    const void* projW, const void* projb, const void* msgW, const void* msgb,
    const void* wih, const void* whh, const void* bih, const void* bhh,
    const void* cw1, const void* cb1, const void* cw2, const void* cb2,
    float* P, u16* PB, const int* flag)
{
    int isbf = *flag;
    int i = blockIdx.x * 256 + threadIdx.x;
    if (i < 19200) P[OFF_PROJW + i] = ldf(projW, i, isbf);
    if (i < 64)    P[OFF_PROJB + i] = ldf(projb, i, isbf);
    if (i < 128)   P[OFF_MSGB + i]  = ldf(msgb, i, isbf);
    if (i < 384)   { P[OFF_BIH + i] = ldf(bih, i, isbf); P[OFF_BHH + i] = ldf(bhh, i, isbf); }
    if (i < 2048)  P[OFF_CW1 + i] = ldf(cw1, i, isbf);
    if (i < 16)    { P[OFF_CB1 + i] = ldf(cb1, i, isbf); P[OFF_CW2 + i] = ldf(cw2, i, isbf); }
    if (i == 0)    P[OFF_CB2] = ldf(cb2, 0, isbf);
    // bf16 weight blocks for MFMA (B-operand layout = [out_row][k], i.e. W as-is; msgW transposed)
    if (i < 24576) {
        PB[PB_WIH + i] = ldb(wih, i, isbf);
        PB[PB_WHH + i] = ldb(whh, i, isbf);
    }
    if (i < 8192) {
        int l = i >> 12, r = i & 4095, j = r >> 6, k = r & 63;
        PB[PB_WMT + i] = ldb(msgW, (long long)l * 4096 + k * 64 + j, isbf);
    }
}

// ---------------- CSR build ----------------
__global__ __launch_bounds__(256) void hist_kernel(const int* adj0, const int* adj1, int* off)
{
    int e = blockIdx.x * 256 + threadIdx.x;
    if (e >= 2 * EE) return;
    int b = e / EE, le = e - b * EE;
    const int* adj = b ? adj1 : adj0;
    int tgt = adj[2 * le + 1];
    atomicAdd(&off[b * (NN + 1) + tgt + 1], 1);
}

__global__ __launch_bounds__(1024) void scan_kernel(int* off, int* cursor)
{
    const int NB = 1024;
    int b = blockIdx.x;
    int* o = off + (size_t)b * (NN + 1);
    int* cur = cursor + (size_t)b * NN;
    __shared__ int buf[NB];
    __shared__ int sbase;
    int tid = threadIdx.x;
    if (tid == 0) sbase = 0;
    __syncthreads();
    for (int start = 0; start < NN; start += NB) {
        int i = start + tid;
        int v = (i < NN) ? o[i + 1] : 0;
        buf[tid] = v;
        __syncthreads();
        for (int s = 1; s < NB; s <<= 1) {
            int t = (tid >= s) ? buf[tid - s] : 0;
            __syncthreads();
            buf[tid] += t;
            __syncthreads();
        }
        int incl = buf[tid];
        int excl = incl - v;
        int base = sbase;
        if (i < NN) { o[i] = base + excl; cur[i] = base + excl; }
        __syncthreads();
        if (tid == NB - 1) sbase = base + incl;
        __syncthreads();
    }
    if (tid == 0) o[NN] = sbase;
}

__global__ __launch_bounds__(256) void scatter_kernel(const int* adj0, const int* adj1,
                                                      int* cursor, int* esrc)
{
    int e = blockIdx.x * 256 + threadIdx.x;
    if (e >= 2 * EE) return;
    int b = e / EE, le = e - b * EE;
    const int* adj = b ? adj1 : adj0;
    int src = adj[2 * le + 0];
    int tgt = adj[2 * le + 1];
    int pos = atomicAdd(&cursor[b * NN + tgt], 1);
    esrc[(size_t)b * EE + pos] = src;
}

// ---------------- embedding gather + projection (h out = bf16) ----------------
__global__ __launch_bounds__(256) void proj_kernel(const void* emb, const int* ind0, const int* ind1,
                                                   const float* P, u16* h, const int* flag)
{
    __shared__ float s_emb[4][EMBD];
    __shared__ float s_W[64 * 64];
    int isbf = *flag;
    int g = threadIdx.x >> 6, lane = threadIdx.x & 63;
    int node = blockIdx.x * 4 + g;
    int b = node >= NN;
    int ln = node - b * NN;
    int idx = b ? ind1[ln] : ind0[ln];
    long long rowoff = (long long)idx * EMBD;
    for (int k = lane; k < EMBD; k += 64) s_emb[g][k] = ldf(emb, rowoff + k, isbf);
    float acc = P[OFF_PROJB + lane];
    for (int k0 = 0; k0 < EMBD; k0 += 64) {
        int kl = (EMBD - k0) < 64 ? (EMBD - k0) : 64;
        __syncthreads();
        for (int t = threadIdx.x; t < kl * 64; t += 256)
            s_W[t] = P[OFF_PROJW + k0 * 64 + t];
        __syncthreads();
        for (int kk = 0; kk < kl; ++kk)
            acc += s_emb[g][k0 + kk] * s_W[kk * 64 + lane];
    }
    h[(size_t)node * 64 + lane] = f2b(acc);
}

// ---------------- neighbor gather-sum (bf16 in / bf16 out, f32 accum) ----------------
__global__ __launch_bounds__(256) void gather_kernel(const u16* h, const int* off,
                                                     const int* esrc, u16* S)
{
    int g = threadIdx.x >> 6, lane = threadIdx.x & 63;
    int node = blockIdx.x * 4 + g;
    int b = node >= NN;
    int ln = node - b * NN;
    const int* o = off + (size_t)b * (NN + 1);
    int s0 = o[ln], s1 = o[ln + 1];
    const int* es = esrc + (size_t)b * EE;
    const u16* hb = h + (size_t)b * NN * 64;
    float acc = 0.f;
    for (int i = s0; i < s1; ++i) {
        int src = es[i];
        acc += b2f(hb[(size_t)src * 64 + lane]);
    }
    S[(size_t)node * 64 + lane] = f2b(acc);
}

// ---------------- fused GRU step: inc = S@msgW + deg*msgb; gi/gh GEMMs; GRU ----
// block = 256 thr (4 waves), 64-node tile; 16x16x32 bf16 MFMA.
// A-frag: A[m=lane&15][k=quad*8+j]; B-frag from W[out][k] row-major (BT layout);
// C-frag: col=lane&15, row=quad*4+reg.
__global__ __launch_bounds__(256) void grustep_kernel(const u16* S, u16* h, const int* ioff,
                                                      const float* P, const u16* PB, int l)
{
    __shared__ u16 s_W[28672];     // Wih 12288 | Whh 12288 | msgWT 4096
    __shared__ u16 s_S[4096];      // S tile -> (aliased) inc tile, wave-private rows
    __shared__ u16 s_h[4096];
    __shared__ float s_deg[64];

    int tid = threadIdx.x;
    int node0 = blockIdx.x * 64;

    // stage weights (uint4 = 8 bf16)
    {
        const uint4* sw = (const uint4*)(PB + PB_WIH + (size_t)l * 12288);
        uint4* dw = (uint4*)(s_W + WIH_S);
        for (int i = tid; i < 1536; i += 256) dw[i] = sw[i];
    }
    {
        const uint4* sw = (const uint4*)(PB + PB_WHH + (size_t)l * 12288);
        uint4* dw = (uint4*)(s_W + WHH_S);
        for (int i = tid; i < 1536; i += 256) dw[i] = sw[i];
    }
    {
        const uint4* sw = (const uint4*)(PB + PB_WMT + (size_t)l * 4096);
        uint4* dw = (uint4*)(s_W + WMT_S);
        for (int i = tid; i < 512; i += 256) dw[i] = sw[i];
    }
    // stage S, h tiles (contiguous, coalesced)
    {
        const uint4* ss = (const uint4*)(S + (size_t)node0 * 64);
        uint4* ds = (uint4*)s_S;
        for (int i = tid; i < 512; i += 256) ds[i] = ss[i];
        const uint4* sh = (const uint4*)(h + (size_t)node0 * 64);
        uint4* dh = (uint4*)s_h;
        for (int i = tid; i < 512; i += 256) dh[i] = sh[i];
    }
    if (tid < 64) {
        int n = node0 + tid;
        int b = n >= NN;
        int ln = n - b * NN;
        const int* o = ioff + (size_t)b * (NN + 1);
        s_deg[tid] = (float)(o[ln + 1] - o[ln]);
    }
    __syncthreads();

    int wv = tid >> 6, lane = tid & 63;
    int m0 = wv * 16, quad = lane >> 4, cn = lane & 15;
    int arow = (m0 + cn) * 64 + quad * 8;

    // ---- phase 1: inc = S @ msgW + deg*msgb (wave-private rows; alias-safe) ----
    s16x8 aS0 = *(const s16x8*)&s_S[arow];
    s16x8 aS1 = *(const s16x8*)&s_S[arow + 32];
    #pragma unroll
    for (int jt = 0; jt < 4; ++jt) {
        int j0 = jt * 16;
        float mb = P[OFF_MSGB + l * 64 + j0 + cn];
        f32x4 acc;
        acc[0] = s_deg[m0 + quad * 4 + 0] * mb;
        acc[1] = s_deg[m0 + quad * 4 + 1] * mb;
        acc[2] = s_deg[m0 + quad * 4 + 2] * mb;
        acc[3] = s_deg[m0 + quad * 4 + 3] * mb;
        int br = WMT_S + (j0 + cn) * 64 + quad * 8;
        acc = __builtin_amdgcn_mfma_f32_16x16x32_bf16(aS0, *(const s16x8*)&s_W[br], acc, 0, 0, 0);
        acc = __builtin_amdgcn_mfma_f32_16x16x32_bf16(aS1, *(const s16x8*)&s_W[br + 32], acc, 0, 0, 0);
        #pragma unroll
        for (int r = 0; r < 4; ++r)
            s_S[(m0 + quad * 4 + r) * 64 + j0 + cn] = f2b(acc[r]);
    }

    // ---- phase 2+3: gi = inc@Wih^T + bih, gh = h@Whh^T + bhh, fused GRU ----
    s16x8 aI0 = *(const s16x8*)&s_S[arow];
    s16x8 aI1 = *(const s16x8*)&s_S[arow + 32];
    s16x8 aH0 = *(const s16x8*)&s_h[arow];
    s16x8 aH1 = *(const s16x8*)&s_h[arow + 32];
    const float* bi = P + OFF_BIH + l * 192;
    const float* bh = P + OFF_BHH + l * 192;

    #pragma unroll
    for (int c = 0; c < 4; ++c) {
        int j0 = c * 16;
        float vr = bi[j0 + cn], vz = bi[64 + j0 + cn], vn = bi[128 + j0 + cn];
        float wr = bh[j0 + cn], wz = bh[64 + j0 + cn], wn = bh[128 + j0 + cn];
        f32x4 gr = {vr, vr, vr, vr}, gz = {vz, vz, vz, vz}, gn = {vn, vn, vn, vn};
        f32x4 hr = {wr, wr, wr, wr}, hz = {wz, wz, wz, wz}, hn = {wn, wn, wn, wn};
        int bir = WIH_S + (j0 + cn) * 64 + quad * 8;
        int biz = WIH_S + (64 + j0 + cn) * 64 + quad * 8;
        int bin_ = WIH_S + (128 + j0 + cn) * 64 + quad * 8;
        int bhr = WHH_S + (j0 + cn) * 64 + quad * 8;
        int bhz = WHH_S + (64 + j0 + cn) * 64 + quad * 8;
        int bhn = WHH_S + (128 + j0 + cn) * 64 + quad * 8;
        gr = __builtin_amdgcn_mfma_f32_16x16x32_bf16(aI0, *(const s16x8*)&s_W[bir], gr, 0, 0, 0);
        gr = __builtin_amdgcn_mfma_f32_16x16x32_bf16(aI1, *(const s16x8*)&s_W[bir + 32], gr, 0, 0, 0);
        gz = __builtin_amdgcn_mfma_f32_16x16x32_bf16(aI0, *(const s16x8*)&s_W[biz], gz, 0, 0, 0);
        gz = __builtin_amdgcn_mfma_f32_16x16x32_bf16(aI1, *(const s16x8*)&s_W[biz + 32], gz, 0, 0, 0);
        gn = __builtin_amdgcn_mfma_f32_16x16x32_bf16(aI0, *(const s16x8*)&s_W[bin_], gn, 0, 0, 0);
        gn = __builtin_amdgcn_mfma_f32_16x16x32_bf16(aI1, *(const s16x8*)&s_W[bin_ + 32], gn, 0, 0, 0);
        hr = __builtin_amdgcn_mfma_f32_16x16x32_bf16(aH0, *(const s16x8*)&s_W[bhr], hr, 0, 0, 0);
        hr = __builtin_amdgcn_mfma_f32_16x16x32_bf16(aH1, *(const s16x8*)&s_W[bhr + 32], hr, 0, 0, 0);
        hz = __builtin_amdgcn_mfma_f32_16x16x32_bf16(aH0, *(const s16x8*)&s_W[bhz], hz, 0, 0, 0);
        hz = __builtin_amdgcn_mfma_f32_16x16x32_bf16(aH1, *(const s16x8*)&s_W[bhz + 32], hz, 0, 0, 0);
        hn = __builtin_amdgcn_mfma_f32_16x16x32_bf16(aH0, *(const s16x8*)&s_W[bhn], hn, 0, 0, 0);
        hn = __builtin_amdgcn_mfma_f32_16x16x32_bf16(aH1, *(const s16x8*)&s_W[bhn + 32], hn, 0, 0, 0);
        #pragma unroll
        for (int r = 0; r < 4; ++r) {
            int row = m0 + quad * 4 + r;
            float rr = 1.f / (1.f + __expf(-(gr[r] + hr[r])));
            float zz = 1.f / (1.f + __expf(-(gz[r] + hz[r])));
            float nn = tanhf(gn[r] + rr * hn[r]);
            float ho = b2f(s_h[row * 64 + j0 + cn]);
            h[(size_t)(node0 + row) * 64 + j0 + cn] = f2b((1.f - zz) * nn + zz * ho);
        }
    }
}

// ---------------- classifier + partial loss ----------------
__global__ __launch_bounds__(256) void cls_kernel(const u16* h, const int* p0, const int* p1,
                                                  const int* labels, const float* P,
                                                  void* out, float* partial, const int* flag)
{
    int isbf = *flag;
    int r = blockIdx.x * 256 + threadIdx.x;
    int n0 = p0[r], n1 = p1[r];
    const u16* h0 = h + (size_t)n0 * 64;
    const u16* h1 = h + (size_t)(NN + n1) * 64;
    float feat[128];
    #pragma unroll
    for (int k = 0; k < 64; ++k) { feat[k] = b2f(h0[k]); feat[64 + k] = b2f(h1[k]); }
    float zacc = P[OFF_CB2];
    #pragma unroll
    for (int t = 0; t < 16; ++t) {
        float a = P[OFF_CB1 + t];
        for (int k = 0; k < 128; ++k) a += feat[k] * P[OFF_CW1 + k * 16 + t];
        a = fmaxf(a, 0.f);
        zacc += a * P[OFF_CW2 + t];
    }
    float p = 1.f / (1.f + expf(-zacc));
    stf(out, r, isbf, p);
    float y = (float)labels[r];
    const float eps = 1e-7f;
    float pc  = fminf(fmaxf(p, eps), 1.f);
    float pc1 = fminf(fmaxf(1.f - p, eps), 1.f);
    float term = y * logf(pc) + (1.f - y) * logf(pc1);
    __shared__ float red[256];
    red[threadIdx.x] = term;
    __syncthreads();
    for (int s = 128; s > 0; s >>= 1) {
        if (threadIdx.x < s) red[threadIdx.x] += red[threadIdx.x + s];
        __syncthreads();
    }
    if (threadIdx.x == 0) partial[blockIdx.x] = red[0];
}

__global__ void loss_kernel(const float* partial, void* out, const int* flag)
{
    if (threadIdx.x == 0 && blockIdx.x == 0) {
        float s = 0.f;
        for (int i = 0; i < 16; ++i) s += partial[i];
        stf(out, BB, *flag, -s / (float)BB);
    }
}

extern "C" void kernel_launch(void* const* d_in, const int* in_sizes, int n_in,
                              void* d_out, int out_size, void* d_ws, size_t ws_size,
                              hipStream_t stream)
{
    const int* adj0     = (const int*)d_in[2];
    const int* adj1     = (const int*)d_in[3];
    const int* prop0    = (const int*)d_in[4];
    const int* prop1    = (const int*)d_in[5];
    const int* labels   = (const int*)d_in[6];

    int* flag = (int*)d_ws;
    float* P  = (float*)d_ws + 16;
    u16* PB   = (u16*)(P + PARAM_SZ);
    u16* hB   = PB + PB_SZ;                    // 40000*64 bf16
    u16* SB   = hB + (size_t)2 * NN * HH;
    float* partial = (float*)(SB + (size_t)2 * NN * HH);
    int* ioff   = (int*)(partial + 64);
    int* cursor = ioff + 2 * (NN + 1) + 62;
    int* esrc   = cursor + 2 * NN;

    hipMemsetAsync(ioff, 0, 2 * (NN + 1) * sizeof(int), stream);

    sniff_kernel<<<1, 64, 0, stream>>>((const u16*)d_in[8], flag);
    conv_kernel<<<96, 256, 0, stream>>>(d_in[8], d_in[9], d_in[10], d_in[11], d_in[12], d_in[13],
                                        d_in[14], d_in[15], d_in[16], d_in[17], d_in[18], d_in[19],
                                        P, PB, flag);
    hist_kernel<<<(2 * EE) / 256, 256, 0, stream>>>(adj0, adj1, ioff);
    scan_kernel<<<2, 1024, 0, stream>>>(ioff, cursor);
    scatter_kernel<<<(2 * EE) / 256, 256, 0, stream>>>(adj0, adj1, cursor, esrc);
    proj_kernel<<<(2 * NN) / 4, 256, 0, stream>>>(d_in[7], (const int*)d_in[0], (const int*)d_in[1],
                                                  P, hB, flag);

    for (int l = 0; l < 2; ++l) {
        for (int t = 0; t < 3; ++t) {
            gather_kernel<<<(2 * NN) / 4, 256, 0, stream>>>(hB, ioff, esrc, SB);
            grustep_kernel<<<(2 * NN) / 64, 256, 0, stream>>>(SB, hB, ioff, P, PB, l);
        }
    }

    cls_kernel<<<BB / 256, 256, 0, stream>>>(hB, prop0, prop1, labels, P, d_out, partial, flag);
    loss_kernel<<<1, 64, 0, stream>>>(partial, d_out, flag);
}

// Round 4
// 569.329 us; speedup vs baseline: 7.7323x; 1.9333x over previous
//
#include <hip/hip_runtime.h>
#include <hip/hip_bf16.h>

typedef unsigned short u16;
typedef __attribute__((ext_vector_type(8))) short s16x8;   // 8 bf16 (4 VGPRs) MFMA A/B frag
typedef __attribute__((ext_vector_type(4))) float f32x4;   // MFMA C/D frag

#define NN 20000
#define HH 64
#define EMBD 300
#define EE 160000
#define BB 4096

// f32 param block offsets (floats) in workspace (after 16-float header)
#define OFF_PROJB 19200
#define OFF_MSGB  19264
#define OFF_BIH   19392
#define OFF_BHH   19776
#define OFF_CW1   20160
#define OFF_CB1   22208
#define OFF_CW2   22224
#define OFF_CB2   22240
#define PARAM_SZ  22272

// bf16 weight blocks (u16 units): Wih[l][192][64] | Whh[l][192][64] | msgWT[l][64][64] | projWT[64][320]
#define PB_WIH   0
#define PB_WHH   24576
#define PB_WMT   49152
#define PB_PROJT 57344
#define PB_SZ    77824

// LDS weight offsets (u16 units) for grustep
#define WIH_S 0
#define WHH_S 12288
#define WMT_S 24576

// projm LDS A-tile row stride (u16): 344 = 320 + 24 -> 172 dwords, 172%32=12 -> <=2-way bank alias
#define APAD 344

__device__ __forceinline__ float b2f(u16 u) {
    union { unsigned int i; float f; } v; v.i = ((unsigned int)u) << 16; return v.f;
}
__device__ __forceinline__ u16 f2b(float f) {
    union { float f; unsigned int u; } v; v.f = f;
    unsigned int u = v.u;
    return (u16)((u + 0x7FFFu + ((u >> 16) & 1u)) >> 16);   // RNE
}
__device__ __forceinline__ float ldf(const void* p, long long i, int isbf) {
    return isbf ? b2f(((const u16*)p)[i]) : ((const float*)p)[i];
}
__device__ __forceinline__ u16 ldb(const void* p, long long i, int isbf) {
    return isbf ? ((const u16*)p)[i] : f2b(((const float*)p)[i]);
}
__device__ __forceinline__ void stf(void* p, long long i, int isbf, float v) {
    if (isbf) ((u16*)p)[i] = f2b(v);
    else      ((float*)p)[i] = v;
}

// ---------------- dtype sniffer (bf16 vs f32 input world) ----------------
__global__ void sniff_kernel(const u16* probe, int* flag)
{
    if (threadIdx.x == 0 && blockIdx.x == 0) {
        int good = 0;
        for (int i = 0; i < 128; i += 2) {
            unsigned int e = (probe[i] >> 7) & 0xFF;
            if (e >= 105 && e <= 127) good++;
        }
        *flag = (good >= 48) ? 1 : 0;
    }
}

// ---------------- param convert ----------------
__global__ __launch_bounds__(256) void conv_kernel(
    const void* projW, const void* projb, const void* msgW, const void* msgb,
    const void* wih, const void* whh, const void* bih, const void* bhh,
    const void* cw1, const void* cb1, const void* cw2, const void* cb2,
    float* P, u16* PB, const int* flag)
{
    int isbf = *flag;
    int i = blockIdx.x * 256 + threadIdx.x;
    if (i < 64)    P[OFF_PROJB + i] = ldf(projb, i, isbf);
    if (i < 128)   P[OFF_MSGB + i]  = ldf(msgb, i, isbf);
    if (i < 384)   { P[OFF_BIH + i] = ldf(bih, i, isbf); P[OFF_BHH + i] = ldf(bhh, i, isbf); }
    if (i < 2048)  P[OFF_CW1 + i] = ldf(cw1, i, isbf);
    if (i < 16)    { P[OFF_CB1 + i] = ldf(cb1, i, isbf); P[OFF_CW2 + i] = ldf(cw2, i, isbf); }
    if (i == 0)    P[OFF_CB2] = ldf(cb2, 0, isbf);
    // bf16 weight blocks for MFMA (B-operand layout = [out_row][k]; msgW/projW transposed)
    if (i < 24576) {
        PB[PB_WIH + i] = ldb(wih, i, isbf);
        PB[PB_WHH + i] = ldb(whh, i, isbf);
    }
    if (i < 8192) {
        int l = i >> 12, r = i & 4095, j = r >> 6, k = r & 63;
        PB[PB_WMT + i] = ldb(msgW, (long long)l * 4096 + k * 64 + j, isbf);
    }
    if (i < 20480) {   // projWT [64][320], zero-padded k>=300
        int n = i / 320, k = i - n * 320;
        PB[PB_PROJT + i] = (k < 300) ? ldb(projW, (long long)k * 64 + n, isbf) : (u16)0;
    }
}

// ---------------- CSR build ----------------
__global__ __launch_bounds__(256) void hist_kernel(const int* __restrict__ adj0,
                                                   const int* __restrict__ adj1, int* off)
{
    int e = blockIdx.x * 256 + threadIdx.x;
    if (e >= 2 * EE) return;
    int b = e / EE, le = e - b * EE;
    const int* adj = b ? adj1 : adj0;
    int tgt = adj[2 * le + 1];
    atomicAdd(&off[b * (NN + 1) + tgt + 1], 1);
}

__global__ __launch_bounds__(1024) void scan_kernel(int* off, int* cursor)
{
    const int NB = 1024;
    int b = blockIdx.x;
    int* o = off + (size_t)b * (NN + 1);
    int* cur = cursor + (size_t)b * NN;
    __shared__ int buf[NB];
    __shared__ int sbase;
    int tid = threadIdx.x;
    if (tid == 0) sbase = 0;
    __syncthreads();
    for (int start = 0; start < NN; start += NB) {
        int i = start + tid;
        int v = (i < NN) ? o[i + 1] : 0;
        buf[tid] = v;
        __syncthreads();
        for (int s = 1; s < NB; s <<= 1) {
            int t = (tid >= s) ? buf[tid - s] : 0;
            __syncthreads();
            buf[tid] += t;
            __syncthreads();
        }
        int incl = buf[tid];
        int excl = incl - v;
        int base = sbase;
        if (i < NN) { o[i] = base + excl; cur[i] = base + excl; }
        __syncthreads();
        if (tid == NB - 1) sbase = base + incl;
        __syncthreads();
    }
    if (tid == 0) o[NN] = sbase;
}

__global__ __launch_bounds__(256) void scatter_kernel(const int* __restrict__ adj0,
                                                      const int* __restrict__ adj1,
                                                      int* cursor, int* esrc)
{
    int e = blockIdx.x * 256 + threadIdx.x;
    if (e >= 2 * EE) return;
    int b = e / EE, le = e - b * EE;
    const int* adj = b ? adj1 : adj0;
    int src = adj[2 * le + 0];
    int tgt = adj[2 * le + 1];
    int pos = atomicAdd(&cursor[b * NN + tgt], 1);
    esrc[(size_t)b * EE + pos] = src;
}

// ---------------- embedding gather + projection, MFMA tile version ----------------
// 64-node tile, 256 threads (4 waves x 16 nodes). A = emb rows staged bf16 in LDS
// (stride APAD); B = projWT [64][320] read as frags directly from global (L2-hot).
__global__ __launch_bounds__(256) void projm_kernel(const void* emb,
                                                    const int* __restrict__ i0,
                                                    const int* __restrict__ i1,
                                                    const float* __restrict__ P,
                                                    const u16* __restrict__ PB,
                                                    u16* __restrict__ h, const int* flag)
{
    __shared__ u16 sA[64 * APAD];
    int isbf = *flag;
    int tid = threadIdx.x;
    int node0 = blockIdx.x * 64;

    // stage 64 embedding rows, 4 threads per row
    {
        int r = tid >> 2, sub = tid & 3;
        int n = node0 + r;
        int b = n >= NN;
        int ln = n - b * NN;
        int idx = b ? i1[ln] : i0[ln];
        if (isbf) {
            const ushort4* src = (const ushort4*)((const u16*)emb + (size_t)idx * EMBD);
            ushort4* dst = (ushort4*)(sA + r * APAD);
            for (int c = sub; c < 75; c += 4) dst[c] = src[c];        // 300 u16 = 75 x 8B exact
            if (sub == 0) {
                ushort4 z = {0, 0, 0, 0};
                for (int c = 75; c < 80; ++c) dst[c] = z;             // zero-pad k=300..319
            }
        } else {
            const float* src = (const float*)emb + (size_t)idx * EMBD;
            for (int k = sub; k < 300; k += 4) sA[r * APAD + k] = f2b(src[k]);
            if (sub == 0) for (int k = 300; k < 320; ++k) sA[r * APAD + k] = 0;
        }
    }
    __syncthreads();

    int wv = tid >> 6, lane = tid & 63, quad = lane >> 4, cn = lane & 15;
    int m0 = wv * 16;
    f32x4 acc[4];
    #pragma unroll
    for (int j = 0; j < 4; ++j) {
        float bb = P[OFF_PROJB + j * 16 + cn];
        acc[j] = {bb, bb, bb, bb};
    }
    #pragma unroll
    for (int k0 = 0; k0 < 320; k0 += 32) {
        s16x8 a = *(const s16x8*)&sA[(m0 + cn) * APAD + k0 + quad * 8];
        #pragma unroll
        for (int j = 0; j < 4; ++j) {
            s16x8 bfr = *(const s16x8*)&PB[PB_PROJT + (j * 16 + cn) * 320 + k0 + quad * 8];
            acc[j] = __builtin_amdgcn_mfma_f32_16x16x32_bf16(a, bfr, acc[j], 0, 0, 0);
        }
    }
    #pragma unroll
    for (int j = 0; j < 4; ++j)
        #pragma unroll
        for (int r = 0; r < 4; ++r)
            h[(size_t)(node0 + m0 + quad * 4 + r) * 64 + j * 16 + cn] = f2b(acc[j][r]);
}

// ---------------- neighbor gather-sum (4-deep ILP) ----------------
__global__ __launch_bounds__(256) void gather_kernel(const u16* __restrict__ h,
                                                     const int* __restrict__ off,
                                                     const int* __restrict__ esrc,
                                                     u16* __restrict__ S)
{
    int g = threadIdx.x >> 6, lane = threadIdx.x & 63;
    int node = blockIdx.x * 4 + g;
    int b = node >= NN;
    int ln = node - b * NN;
    const int* o = off + (size_t)b * (NN + 1);
    int s0 = o[ln], s1 = o[ln + 1];
    const int* es = esrc + (size_t)b * EE;
    const u16* hb = h + (size_t)b * NN * 64;
    float a0 = 0.f, a1 = 0.f, a2 = 0.f, a3 = 0.f;
    int i = s0;
    for (; i + 4 <= s1; i += 4) {
        int e0 = es[i], e1 = es[i + 1], e2 = es[i + 2], e3 = es[i + 3];
        a0 += b2f(hb[(size_t)e0 * 64 + lane]);
        a1 += b2f(hb[(size_t)e1 * 64 + lane]);
        a2 += b2f(hb[(size_t)e2 * 64 + lane]);
        a3 += b2f(hb[(size_t)e3 * 64 + lane]);
    }
    for (; i < s1; ++i) a0 += b2f(hb[(size_t)es[i] * 64 + lane]);
    S[(size_t)node * 64 + lane] = f2b(a0 + a1 + a2 + a3);
}

// ---------------- fused GRU step (MFMA) ----------------
__global__ __launch_bounds__(256) void grustep_kernel(const u16* __restrict__ S,
                                                      u16* __restrict__ h,
                                                      const int* __restrict__ ioff,
                                                      const float* __restrict__ P,
                                                      const u16* __restrict__ PB, int l)
{
    __shared__ u16 s_W[28672];     // Wih 12288 | Whh 12288 | msgWT 4096
    __shared__ u16 s_S[4096];
    __shared__ u16 s_h[4096];
    __shared__ float s_deg[64];

    int tid = threadIdx.x;
    int node0 = blockIdx.x * 64;

    {
        const uint4* sw = (const uint4*)(PB + PB_WIH + (size_t)l * 12288);
        uint4* dw = (uint4*)(s_W + WIH_S);
        for (int i = tid; i < 1536; i += 256) dw[i] = sw[i];
    }
    {
        const uint4* sw = (const uint4*)(PB + PB_WHH + (size_t)l * 12288);
        uint4* dw = (uint4*)(s_W + WHH_S);
        for (int i = tid; i < 1536; i += 256) dw[i] = sw[i];
    }
    {
        const uint4* sw = (const uint4*)(PB + PB_WMT + (size_t)l * 4096);
        uint4* dw = (uint4*)(s_W + WMT_S);
        for (int i = tid; i < 512; i += 256) dw[i] = sw[i];
    }
    {
        const uint4* ss = (const uint4*)(S + (size_t)node0 * 64);
        uint4* ds = (uint4*)s_S;
        for (int i = tid; i < 512; i += 256) ds[i] = ss[i];
        const uint4* sh = (const uint4*)(h + (size_t)node0 * 64);
        uint4* dh = (uint4*)s_h;
        for (int i = tid; i < 512; i += 256) dh[i] = sh[i];
    }
    if (tid < 64) {
        int n = node0 + tid;
        int b = n >= NN;
        int ln = n - b * NN;
        const int* o = ioff + (size_t)b * (NN + 1);
        s_deg[tid] = (float)(o[ln + 1] - o[ln]);
    }
    __syncthreads();

    int wv = tid >> 6, lane = tid & 63;
    int m0 = wv * 16, quad = lane >> 4, cn = lane & 15;
    int arow = (m0 + cn) * 64 + quad * 8;

    // phase 1: inc = S @ msgW + deg*msgb (wave-private rows; alias-safe)
    s16x8 aS0 = *(const s16x8*)&s_S[arow];
    s16x8 aS1 = *(const s16x8*)&s_S[arow + 32];
    #pragma unroll
    for (int jt = 0; jt < 4; ++jt) {
        int j0 = jt * 16;
        float mb = P[OFF_MSGB + l * 64 + j0 + cn];
        f32x4 acc;
        acc[0] = s_deg[m0 + quad * 4 + 0] * mb;
        acc[1] = s_deg[m0 + quad * 4 + 1] * mb;
        acc[2] = s_deg[m0 + quad * 4 + 2] * mb;
        acc[3] = s_deg[m0 + quad * 4 + 3] * mb;
        int br = WMT_S + (j0 + cn) * 64 + quad * 8;
        acc = __builtin_amdgcn_mfma_f32_16x16x32_bf16(aS0, *(const s16x8*)&s_W[br], acc, 0, 0, 0);
        acc = __builtin_amdgcn_mfma_f32_16x16x32_bf16(aS1, *(const s16x8*)&s_W[br + 32], acc, 0, 0, 0);
        #pragma unroll
        for (int r = 0; r < 4; ++r)
            s_S[(m0 + quad * 4 + r) * 64 + j0 + cn] = f2b(acc[r]);
    }

    // phase 2+3: gi/gh GEMMs + fused GRU
    s16x8 aI0 = *(const s16x8*)&s_S[arow];
    s16x8 aI1 = *(const s16x8*)&s_S[arow + 32];
    s16x8 aH0 = *(const s16x8*)&s_h[arow];
    s16x8 aH1 = *(const s16x8*)&s_h[arow + 32];
    const float* bi = P + OFF_BIH + l * 192;
    const float* bh = P + OFF_BHH + l * 192;

    #pragma unroll
    for (int c = 0; c < 4; ++c) {
        int j0 = c * 16;
        float vr = bi[j0 + cn], vz = bi[64 + j0 + cn], vn = bi[128 + j0 + cn];
        float wr = bh[j0 + cn], wz = bh[64 + j0 + cn], wn = bh[128 + j0 + cn];
        f32x4 gr = {vr, vr, vr, vr}, gz = {vz, vz, vz, vz}, gn = {vn, vn, vn, vn};
        f32x4 hr = {wr, wr, wr, wr}, hz = {wz, wz, wz, wz}, hn = {wn, wn, wn, wn};
        int bir = WIH_S + (j0 + cn) * 64 + quad * 8;
        int biz = WIH_S + (64 + j0 + cn) * 64 + quad * 8;
        int bin_ = WIH_S + (128 + j0 + cn) * 64 + quad * 8;
        int bhr = WHH_S + (j0 + cn) * 64 + quad * 8;
        int bhz = WHH_S + (64 + j0 + cn) * 64 + quad * 8;
        int bhn = WHH_S + (128 + j0 + cn) * 64 + quad * 8;
        gr = __builtin_amdgcn_mfma_f32_16x16x32_bf16(aI0, *(const s16x8*)&s_W[bir], gr, 0, 0, 0);
        gr = __builtin_amdgcn_mfma_f32_16x16x32_bf16(aI1, *(const s16x8*)&s_W[bir + 32], gr, 0, 0, 0);
        gz = __builtin_amdgcn_mfma_f32_16x16x32_bf16(aI0, *(const s16x8*)&s_W[biz], gz, 0, 0, 0);
        gz = __builtin_amdgcn_mfma_f32_16x16x32_bf16(aI1, *(const s16x8*)&s_W[biz + 32], gz, 0, 0, 0);
        gn = __builtin_amdgcn_mfma_f32_16x16x32_bf16(aI0, *(const s16x8*)&s_W[bin_], gn, 0, 0, 0);
        gn = __builtin_amdgcn_mfma_f32_16x16x32_bf16(aI1, *(const s16x8*)&s_W[bin_ + 32], gn, 0, 0, 0);
        hr = __builtin_amdgcn_mfma_f32_16x16x32_bf16(aH0, *(const s16x8*)&s_W[bhr], hr, 0, 0, 0);
        hr = __builtin_amdgcn_mfma_f32_16x16x32_bf16(aH1, *(const s16x8*)&s_W[bhr + 32], hr, 0, 0, 0);
        hz = __builtin_amdgcn_mfma_f32_16x16x32_bf16(aH0, *(const s16x8*)&s_W[bhz], hz, 0, 0, 0);
        hz = __builtin_amdgcn_mfma_f32_16x16x32_bf16(aH1, *(const s16x8*)&s_W[bhz + 32], hz, 0, 0, 0);
        hn = __builtin_amdgcn_mfma_f32_16x16x32_bf16(aH0, *(const s16x8*)&s_W[bhn], hn, 0, 0, 0);
        hn = __builtin_amdgcn_mfma_f32_16x16x32_bf16(aH1, *(const s16x8*)&s_W[bhn + 32], hn, 0, 0, 0);
        #pragma unroll
        for (int r = 0; r < 4; ++r) {
            int row = m0 + quad * 4 + r;
            float rr = 1.f / (1.f + __expf(-(gr[r] + hr[r])));
            float zz = 1.f / (1.f + __expf(-(gz[r] + hz[r])));
            float nn = tanhf(gn[r] + rr * hn[r]);
            float ho = b2f(s_h[row * 64 + j0 + cn]);
            h[(size_t)(node0 + row) * 64 + j0 + cn] = f2b((1.f - zz) * nn + zz * ho);
        }
    }
}

// ---------------- classifier + partial loss ----------------
__global__ __launch_bounds__(256) void cls_kernel(const u16* __restrict__ h,
                                                  const int* __restrict__ p0,
                                                  const int* __restrict__ p1,
                                                  const int* __restrict__ labels,
                                                  const float* __restrict__ P,
                                                  void* out, float* partial, const int* flag)
{
    int isbf = *flag;
    int r = blockIdx.x * 256 + threadIdx.x;
    int n0 = p0[r], n1 = p1[r];
    const u16* h0 = h + (size_t)n0 * 64;
    const u16* h1 = h + (size_t)(NN + n1) * 64;
    float feat[128];
    #pragma unroll
    for (int k = 0; k < 64; ++k) { feat[k] = b2f(h0[k]); feat[64 + k] = b2f(h1[k]); }
    float zacc = P[OFF_CB2];
    #pragma unroll
    for (int t = 0; t < 16; ++t) {
        float a = P[OFF_CB1 + t];
        for (int k = 0; k < 128; ++k) a += feat[k] * P[OFF_CW1 + k * 16 + t];
        a = fmaxf(a, 0.f);
        zacc += a * P[OFF_CW2 + t];
    }
    float p = 1.f / (1.f + expf(-zacc));
    stf(out, r, isbf, p);
    float y = (float)labels[r];
    const float eps = 1e-7f;
    float pc  = fminf(fmaxf(p, eps), 1.f);
    float pc1 = fminf(fmaxf(1.f - p, eps), 1.f);
    float term = y * logf(pc) + (1.f - y) * logf(pc1);
    __shared__ float red[256];
    red[threadIdx.x] = term;
    __syncthreads();
    for (int s = 128; s > 0; s >>= 1) {
        if (threadIdx.x < s) red[threadIdx.x] += red[threadIdx.x + s];
        __syncthreads();
    }
    if (threadIdx.x == 0) partial[blockIdx.x] = red[0];
}

__global__ void loss_kernel(const float* partial, void* out, const int* flag)
{
    if (threadIdx.x == 0 && blockIdx.x == 0) {
        float s = 0.f;
        for (int i = 0; i < 16; ++i) s += partial[i];
        stf(out, BB, *flag, -s / (float)BB);
    }
}

extern "C" void kernel_launch(void* const* d_in, const int* in_sizes, int n_in,
                              void* d_out, int out_size, void* d_ws, size_t ws_size,
                              hipStream_t stream)
{
    const int* adj0     = (const int*)d_in[2];
    const int* adj1     = (const int*)d_in[3];
    const int* prop0    = (const int*)d_in[4];
    const int* prop1    = (const int*)d_in[5];
    const int* labels   = (const int*)d_in[6];

    int* flag = (int*)d_ws;
    float* P  = (float*)d_ws + 16;
    u16* PB   = (u16*)(P + PARAM_SZ);
    u16* hB   = PB + PB_SZ;                    // 40000*64 bf16
    u16* SB   = hB + (size_t)2 * NN * HH;
    float* partial = (float*)(SB + (size_t)2 * NN * HH);
    int* ioff   = (int*)(partial + 64);
    int* cursor = ioff + 2 * (NN + 1) + 62;
    int* esrc   = cursor + 2 * NN;

    hipMemsetAsync(ioff, 0, 2 * (NN + 1) * sizeof(int), stream);

    sniff_kernel<<<1, 64, 0, stream>>>((const u16*)d_in[8], flag);
    conv_kernel<<<96, 256, 0, stream>>>(d_in[8], d_in[9], d_in[10], d_in[11], d_in[12], d_in[13],
                                        d_in[14], d_in[15], d_in[16], d_in[17], d_in[18], d_in[19],
                                        P, PB, flag);
    hist_kernel<<<(2 * EE) / 256, 256, 0, stream>>>(adj0, adj1, ioff);
    scan_kernel<<<2, 1024, 0, stream>>>(ioff, cursor);
    scatter_kernel<<<(2 * EE) / 256, 256, 0, stream>>>(adj0, adj1, cursor, esrc);
    projm_kernel<<<(2 * NN) / 64, 256, 0, stream>>>(d_in[7], (const int*)d_in[0],
                                                    (const int*)d_in[1], P, PB, hB, flag);

    for (int l = 0; l < 2; ++l) {
        for (int t = 0; t < 3; ++t) {
            gather_kernel<<<(2 * NN) / 4, 256, 0, stream>>>(hB, ioff, esrc, SB);
            grustep_kernel<<<(2 * NN) / 64, 256, 0, stream>>>(SB, hB, ioff, P, PB, l);
        }
    }

    cls_kernel<<<BB / 256, 256, 0, stream>>>(hB, prop0, prop1, labels, P, d_out, partial, flag);
    loss_kernel<<<1, 64, 0, stream>>>(partial, d_out, flag);
}

// Round 6
// 546.654 us; speedup vs baseline: 8.0530x; 1.0415x over previous
//
#include <hip/hip_runtime.h>
#include <hip/hip_bf16.h>

typedef unsigned short u16;
typedef __attribute__((ext_vector_type(8))) short s16x8;   // 8 bf16 MFMA A/B frag
typedef __attribute__((ext_vector_type(4))) float f32x4;   // MFMA C/D frag

#define NN 20000
#define HH 64
#define EMBD 300
#define EE 160000
#define BB 4096

// f32 param block offsets (floats) in workspace (after 16-float header)
#define OFF_PROJB 0
#define OFF_MSGB  64
#define OFF_BIH   192
#define OFF_BHH   576
#define OFF_CW1T  960
#define OFF_CB1   3008
#define OFF_CW2   3024
#define OFF_CB2   3040
#define PARAM_SZ  3072

// bf16 frag-swizzled weight blocks (u16 units). Each "frag" = 512 u16 = one
// 16(row)x32(k) B-tile stored so lane L reads its 8 elements at frag*512+L*8
// (fully coalesced 1KB global load). row = jt*16+(L&15), k = kt*32+(L>>4)*8+e.
#define PB_WIH   0        // 2 l x 24 frags (jt 0..11, kt 0..1)
#define PB_WHH   24576
#define PB_WMT   49152    // 2 l x 8 frags (jt 0..3, kt 0..1)
#define PB_PROJT 57344    // 40 frags (frag = jt*10+kt, jt 0..3, kt 0..9)
#define PB_SZ    77824

// projm LDS A-tile row stride (u16): 344 -> 172 dwords, <=2-way bank alias (free)
#define APAD 344

__device__ __forceinline__ float b2f(u16 u) {
    union { unsigned int i; float f; } v; v.i = ((unsigned int)u) << 16; return v.f;
}
__device__ __forceinline__ u16 f2b(float f) {
    union { float f; unsigned int u; } v; v.f = f;
    unsigned int u = v.u;
    return (u16)((u + 0x7FFFu + ((u >> 16) & 1u)) >> 16);   // RNE
}
__device__ __forceinline__ float ldf(const void* p, long long i, int isbf) {
    return isbf ? b2f(((const u16*)p)[i]) : ((const float*)p)[i];
}
__device__ __forceinline__ u16 ldb(const void* p, long long i, int isbf) {
    return isbf ? ((const u16*)p)[i] : f2b(((const float*)p)[i]);
}
__device__ __forceinline__ void stf(void* p, long long i, int isbf, float v) {
    if (isbf) ((u16*)p)[i] = f2b(v);
    else      ((float*)p)[i] = v;
}

// ---------------- dtype sniffer ----------------
__global__ void sniff_kernel(const u16* probe, int* flag)
{
    if (threadIdx.x == 0 && blockIdx.x == 0) {
        int good = 0;
        for (int i = 0; i < 128; i += 2) {
            unsigned int e = (probe[i] >> 7) & 0xFF;
            if (e >= 105 && e <= 127) good++;
        }
        *flag = (good >= 48) ? 1 : 0;
    }
}

// ---------------- param convert + frag swizzle ----------------
__global__ __launch_bounds__(256) void conv_kernel(
    const void* projW, const void* projb, const void* msgW, const void* msgb,
    const void* wih, const void* whh, const void* bih, const void* bhh,
    const void* cw1, const void* cb1, const void* cw2, const void* cb2,
    float* P, u16* PB, const int* flag)
{
    int isbf = *flag;
    int i = blockIdx.x * 256 + threadIdx.x;
    if (i < 64)    P[OFF_PROJB + i] = ldf(projb, i, isbf);
    if (i < 128)   P[OFF_MSGB + i]  = ldf(msgb, i, isbf);
    if (i < 384)   { P[OFF_BIH + i] = ldf(bih, i, isbf); P[OFF_BHH + i] = ldf(bhh, i, isbf); }
    if (i < 2048)  { int t = i >> 7, k = i & 127; P[OFF_CW1T + i] = ldf(cw1, (long long)k * 16 + t, isbf); }
    if (i < 16)    { P[OFF_CB1 + i] = ldf(cb1, i, isbf); P[OFF_CW2 + i] = ldf(cw2, i, isbf); }
    if (i == 0)    P[OFF_CB2] = ldf(cb2, 0, isbf);

    if (i < 24576) {   // Wih/Whh swizzle: per-l 24 frags
        int l = i / 12288, r = i - l * 12288;
        int frag = r >> 9, rr = r & 511, lane = rr >> 3, e = rr & 7;
        int jt = frag >> 1, kt = frag & 1;
        int srow = jt * 16 + (lane & 15);
        int sk = kt * 32 + ((lane >> 4) << 3) + e;
        long long si = (long long)l * 12288 + srow * 64 + sk;
        PB[PB_WIH + i] = ldb(wih, si, isbf);
        PB[PB_WHH + i] = ldb(whh, si, isbf);
    }
    if (i < 8192) {    // msgW^T swizzle: B row = output col j of msgW
        int l = i >> 12, r = i & 4095;
        int frag = r >> 9, rr = r & 511, lane = rr >> 3, e = rr & 7;
        int jt = frag >> 1, kt = frag & 1;
        int srow = jt * 16 + (lane & 15);
        int sk = kt * 32 + ((lane >> 4) << 3) + e;
        PB[PB_WMT + i] = ldb(msgW, (long long)l * 4096 + sk * 64 + srow, isbf);
    }
    if (i < 20480) {   // projW^T swizzle: frag = jt*10+kt, k zero-padded >=300
        int frag = i >> 9, rr = i & 511, lane = rr >> 3, e = rr & 7;
        int jt = frag / 10, kt = frag - jt * 10;
        int srow = jt * 16 + (lane & 15);
        int sk = kt * 32 + ((lane >> 4) << 3) + e;
        PB[PB_PROJT + i] = (sk < 300) ? ldb(projW, (long long)sk * 64 + srow, isbf) : (u16)0;
    }
}

// ---------------- CSR build ----------------
__global__ __launch_bounds__(256) void hist_kernel(const int* __restrict__ adj0,
                                                   const int* __restrict__ adj1, int* off)
{
    int e = blockIdx.x * 256 + threadIdx.x;
    if (e >= 2 * EE) return;
    int b = e / EE, le = e - b * EE;
    const int* adj = b ? adj1 : adj0;
    int tgt = adj[2 * le + 1];
    atomicAdd(&off[b * (NN + 1) + tgt + 1], 1);
}

// shuffle-based scan: 2 barriers per 1024-chunk
__global__ __launch_bounds__(1024) void scan_kernel(int* off, int* cursor)
{
    int b = blockIdx.x;
    int* o = off + (size_t)b * (NN + 1);
    int* cur = cursor + (size_t)b * NN;
    __shared__ int wsum[16];
    __shared__ int wscan[16];
    int tid = threadIdx.x, wv = tid >> 6, lane = tid & 63;
    int base = 0;
    for (int start = 0; start < NN; start += 1024) {
        int i = start + tid;
        int v = (i < NN) ? o[i + 1] : 0;
        int orig = v;
        #pragma unroll
        for (int d = 1; d < 64; d <<= 1) {
            int t = __shfl_up(v, d);
            if (lane >= d) v += t;
        }
        if (lane == 63) wsum[wv] = v;
        __syncthreads();
        if (tid < 16) {
            int w = wsum[tid];
            #pragma unroll
            for (int d = 1; d < 16; d <<= 1) {
                int t = __shfl_up(w, d, 16);
                if (tid >= d) w += t;
            }
            wscan[tid] = w;
        }
        __syncthreads();
        int woff = (wv == 0) ? 0 : wscan[wv - 1];
        int excl = base + woff + v - orig;
        if (i < NN) { o[i] = excl; cur[i] = excl; }
        base += wscan[15];
    }
    if (tid == 0) o[NN] = base;
}

__global__ __launch_bounds__(256) void scatter_kernel(const int* __restrict__ adj0,
                                                      const int* __restrict__ adj1,
                                                      int* cursor, int* esrc)
{
    int e = blockIdx.x * 256 + threadIdx.x;
    if (e >= 2 * EE) return;
    int b = e / EE, le = e - b * EE;
    const int* adj = b ? adj1 : adj0;
    int src = adj[2 * le + 0];
    int tgt = adj[2 * le + 1];
    int pos = atomicAdd(&cursor[b * NN + tgt], 1);
    esrc[(size_t)b * EE + pos] = src;
}

// ---------------- embedding gather + projection (MFMA, swizzled global B) ----
__global__ __launch_bounds__(256) void projm_kernel(const void* emb,
                                                    const int* __restrict__ i0,
                                                    const int* __restrict__ i1,
                                                    const float* __restrict__ P,
                                                    const u16* __restrict__ PB,
                                                    u16* __restrict__ h, const int* flag)
{
    __shared__ u16 sA[64 * APAD];
    int isbf = *flag;
    int tid = threadIdx.x;
    int node0 = blockIdx.x * 64;

    // stage 64 embedding rows, 4 threads per row (wave w stages+reads rows 16w..16w+15)
    {
        int r = tid >> 2, sub = tid & 3;
        int n = node0 + r;
        int b = n >= NN;
        int ln = n - b * NN;
        int idx = b ? i1[ln] : i0[ln];
        if (isbf) {
            const ushort4* src = (const ushort4*)((const u16*)emb + (size_t)idx * EMBD);
            ushort4* dst = (ushort4*)(sA + r * APAD);
            for (int c = sub; c < 75; c += 4) dst[c] = src[c];
            if (sub == 0) {
                ushort4 z = {0, 0, 0, 0};
                for (int c = 75; c < 80; ++c) dst[c] = z;
            }
        } else {
            const float* src = (const float*)emb + (size_t)idx * EMBD;
            for (int k = sub; k < 300; k += 4) sA[r * APAD + k] = f2b(src[k]);
            if (sub == 0) for (int k = 300; k < 320; ++k) sA[r * APAD + k] = 0;
        }
    }

    int wv = tid >> 6, lane = tid & 63, quad = lane >> 4, cn = lane & 15;
    int m0 = wv * 16;
    f32x4 acc[4];
    #pragma unroll
    for (int j = 0; j < 4; ++j) {
        float bb = P[OFF_PROJB + j * 16 + cn];
        acc[j] = {bb, bb, bb, bb};
    }
    #pragma unroll
    for (int kt = 0; kt < 10; ++kt) {
        s16x8 a = *(const s16x8*)&sA[(m0 + cn) * APAD + kt * 32 + quad * 8];
        #pragma unroll
        for (int j = 0; j < 4; ++j) {
            s16x8 bfr = *(const s16x8*)&PB[PB_PROJT + (j * 10 + kt) * 512 + lane * 8];
            acc[j] = __builtin_amdgcn_mfma_f32_16x16x32_bf16(a, bfr, acc[j], 0, 0, 0);
        }
    }
    #pragma unroll
    for (int j = 0; j < 4; ++j)
        #pragma unroll
        for (int r = 0; r < 4; ++r)
            h[(size_t)(node0 + m0 + quad * 4 + r) * 64 + j * 16 + cn] = f2b(acc[j][r]);
}

// ---------------- fused gather + GRU step (double-buffered h, barrier-free) ----
__global__ __launch_bounds__(256) void gstep_kernel(const u16* __restrict__ h_old,
                                                    u16* __restrict__ h_new,
                                                    const int* __restrict__ ioff,
                                                    const int* __restrict__ esrc,
                                                    const float* __restrict__ P,
                                                    const u16* __restrict__ PB, int l)
{
    __shared__ u16 s_S[4096];
    __shared__ u16 s_h[4096];
    __shared__ float s_deg[64];

    int tid = threadIdx.x;
    int wv = tid >> 6, lane = tid & 63;
    int node0 = blockIdx.x * 64;
    int m0 = wv * 16;

    // stage own h rows (wave-private: wave w rows 16w..16w+15)
    {
        const uint4* src = (const uint4*)(h_old + (size_t)(node0 + m0) * 64);
        uint4* dst = (uint4*)(s_h + m0 * 64);
        dst[lane] = src[lane];
        dst[lane + 64] = src[lane + 64];
    }

    // gather S rows (wave-private), 4-deep ILP per node
    for (int j = 0; j < 16; ++j) {
        int row = m0 + j;
        int n = node0 + row;
        int b = n >= NN;
        int ln = n - b * NN;
        const int* o = ioff + (size_t)b * (NN + 1);
        int s0 = o[ln], s1 = o[ln + 1];
        const int* es = esrc + (size_t)b * EE;
        const u16* hb = h_old + (size_t)b * NN * 64;
        float a0 = 0.f, a1 = 0.f, a2 = 0.f, a3 = 0.f;
        int i = s0;
        for (; i + 4 <= s1; i += 4) {
            int e0 = es[i], e1 = es[i + 1], e2 = es[i + 2], e3 = es[i + 3];
            a0 += b2f(hb[(size_t)e0 * 64 + lane]);
            a1 += b2f(hb[(size_t)e1 * 64 + lane]);
            a2 += b2f(hb[(size_t)e2 * 64 + lane]);
            a3 += b2f(hb[(size_t)e3 * 64 + lane]);
        }
        for (; i < s1; ++i) a0 += b2f(hb[(size_t)es[i] * 64 + lane]);
        s_S[row * 64 + lane] = f2b(a0 + a1 + a2 + a3);
        if (lane == 0) s_deg[row] = (float)(s1 - s0);
    }

    int quad = lane >> 4, cn = lane & 15;
    int arow = (m0 + cn) * 64 + quad * 8;
    int fl = lane * 8;

    // phase 1: inc = S @ msgW + deg*msgb (wave-private rows, alias-safe)
    s16x8 aS0 = *(const s16x8*)&s_S[arow];
    s16x8 aS1 = *(const s16x8*)&s_S[arow + 32];
    const u16* WM = PB + PB_WMT + (size_t)l * 4096;
    #pragma unroll
    for (int jt = 0; jt < 4; ++jt) {
        float mb = P[OFF_MSGB + l * 64 + jt * 16 + cn];
        f32x4 acc;
        acc[0] = s_deg[m0 + quad * 4 + 0] * mb;
        acc[1] = s_deg[m0 + quad * 4 + 1] * mb;
        acc[2] = s_deg[m0 + quad * 4 + 2] * mb;
        acc[3] = s_deg[m0 + quad * 4 + 3] * mb;
        acc = __builtin_amdgcn_mfma_f32_16x16x32_bf16(aS0, *(const s16x8*)&WM[(jt * 2 + 0) * 512 + fl], acc, 0, 0, 0);
        acc = __builtin_amdgcn_mfma_f32_16x16x32_bf16(aS1, *(const s16x8*)&WM[(jt * 2 + 1) * 512 + fl], acc, 0, 0, 0);
        #pragma unroll
        for (int r = 0; r < 4; ++r)
            s_S[(m0 + quad * 4 + r) * 64 + jt * 16 + cn] = f2b(acc[r]);
    }

    // phase 2+3: gi/gh GEMMs (B-frags coalesced from global) + fused GRU
    s16x8 aI0 = *(const s16x8*)&s_S[arow];
    s16x8 aI1 = *(const s16x8*)&s_S[arow + 32];
    s16x8 aH0 = *(const s16x8*)&s_h[arow];
    s16x8 aH1 = *(const s16x8*)&s_h[arow + 32];
    const u16* WI = PB + PB_WIH + (size_t)l * 12288;
    const u16* WH = PB + PB_WHH + (size_t)l * 12288;
    const float* bi = P + OFF_BIH + l * 192;
    const float* bh = P + OFF_BHH + l * 192;

    #pragma unroll
    for (int c = 0; c < 4; ++c) {
        int j0 = c * 16;
        float vr = bi[j0 + cn], vz = bi[64 + j0 + cn], vn = bi[128 + j0 + cn];
        float wr = bh[j0 + cn], wz = bh[64 + j0 + cn], wn = bh[128 + j0 + cn];
        f32x4 gr = {vr, vr, vr, vr}, gz = {vz, vz, vz, vz}, gn = {vn, vn, vn, vn};
        f32x4 hr = {wr, wr, wr, wr}, hz = {wz, wz, wz, wz}, hn = {wn, wn, wn, wn};
        int fr = (c * 2) * 512 + fl, frz = ((4 + c) * 2) * 512 + fl, frn = ((8 + c) * 2) * 512 + fl;
        gr = __builtin_amdgcn_mfma_f32_16x16x32_bf16(aI0, *(const s16x8*)&WI[fr], gr, 0, 0, 0);
        gr = __builtin_amdgcn_mfma_f32_16x16x32_bf16(aI1, *(const s16x8*)&WI[fr + 512], gr, 0, 0, 0);
        gz = __builtin_amdgcn_mfma_f32_16x16x32_bf16(aI0, *(const s16x8*)&WI[frz], gz, 0, 0, 0);
        gz = __builtin_amdgcn_mfma_f32_16x16x32_bf16(aI1, *(const s16x8*)&WI[frz + 512], gz, 0, 0, 0);
        gn = __builtin_amdgcn_mfma_f32_16x16x32_bf16(aI0, *(const s16x8*)&WI[frn], gn, 0, 0, 0);
        gn = __builtin_amdgcn_mfma_f32_16x16x32_bf16(aI1, *(const s16x8*)&WI[frn + 512], gn, 0, 0, 0);
        hr = __builtin_amdgcn_mfma_f32_16x16x32_bf16(aH0, *(const s16x8*)&WH[fr], hr, 0, 0, 0);
        hr = __builtin_amdgcn_mfma_f32_16x16x32_bf16(aH1, *(const s16x8*)&WH[fr + 512], hr, 0, 0, 0);
        hz = __builtin_amdgcn_mfma_f32_16x16x32_bf16(aH0, *(const s16x8*)&WH[frz], hz, 0, 0, 0);
        hz = __builtin_amdgcn_mfma_f32_16x16x32_bf16(aH1, *(const s16x8*)&WH[frz + 512], hz, 0, 0, 0);
        hn = __builtin_amdgcn_mfma_f32_16x16x32_bf16(aH0, *(const s16x8*)&WH[frn], hn, 0, 0, 0);
        hn = __builtin_amdgcn_mfma_f32_16x16x32_bf16(aH1, *(const s16x8*)&WH[frn + 512], hn, 0, 0, 0);
        #pragma unroll
        for (int r = 0; r < 4; ++r) {
            int row = m0 + quad * 4 + r;
            float rr = 1.f / (1.f + __expf(-(gr[r] + hr[r])));
            float zz = 1.f / (1.f + __expf(-(gz[r] + hz[r])));
            float nn = tanhf(gn[r] + rr * hn[r]);
            float ho = b2f(s_h[row * 64 + j0 + cn]);
            h_new[(size_t)(node0 + row) * 64 + j0 + cn] = f2b((1.f - zz) * nn + zz * ho);
        }
    }
}

// ---------------- classifier: wave-per-sample, coalesced, shuffle-reduce ------
__global__ __launch_bounds__(256) void cls_kernel(const u16* __restrict__ h,
                                                  const int* __restrict__ p0,
                                                  const int* __restrict__ p1,
                                                  const int* __restrict__ labels,
                                                  const float* __restrict__ P,
                                                  void* out, float* partial, const int* flag)
{
    int isbf = *flag;
    int wv = threadIdx.x >> 6, lane = threadIdx.x & 63;
    int s = blockIdx.x * 4 + wv;               // 1024 blocks x 4 waves = 4096
    int n0 = p0[s], n1 = p1[s];
    float f0 = b2f(h[(size_t)n0 * 64 + lane]);
    float f1 = b2f(h[((size_t)NN + n1) * 64 + lane]);
    float z = P[OFF_CB2];
    #pragma unroll
    for (int t = 0; t < 16; ++t) {
        float part = f0 * P[OFF_CW1T + t * 128 + lane] + f1 * P[OFF_CW1T + t * 128 + 64 + lane];
        #pragma unroll
        for (int off = 32; off; off >>= 1) part += __shfl_xor(part, off);
        z += fmaxf(part + P[OFF_CB1 + t], 0.f) * P[OFF_CW2 + t];
    }
    float p = 1.f / (1.f + expf(-z));
    float y = (float)labels[s];
    const float eps = 1e-7f;
    float pc  = fminf(fmaxf(p, eps), 1.f);
    float pc1 = fminf(fmaxf(1.f - p, eps), 1.f);
    float term = y * logf(pc) + (1.f - y) * logf(pc1);
    __shared__ float red[4];
    if (lane == 0) { stf(out, s, isbf, p); red[wv] = term; }
    __syncthreads();
    if (threadIdx.x == 0) partial[blockIdx.x] = red[0] + red[1] + red[2] + red[3];
}

__global__ __launch_bounds__(256) void loss_kernel(const float* __restrict__ partial,
                                                   void* out, const int* flag)
{
    __shared__ float red[256];
    int tid = threadIdx.x;
    float s = 0.f;
    for (int i = tid; i < 1024; i += 256) s += partial[i];
    red[tid] = s;
    __syncthreads();
    for (int d = 128; d > 0; d >>= 1) {
        if (tid < d) red[tid] += red[tid + d];
        __syncthreads();
    }
    if (tid == 0) stf(out, BB, *flag, -red[0] / (float)BB);
}

extern "C" void kernel_launch(void* const* d_in, const int* in_sizes, int n_in,
                              void* d_out, int out_size, void* d_ws, size_t ws_size,
                              hipStream_t stream)
{
    const int* adj0   = (const int*)d_in[2];
    const int* adj1   = (const int*)d_in[3];
    const int* prop0  = (const int*)d_in[4];
    const int* prop1  = (const int*)d_in[5];
    const int* labels = (const int*)d_in[6];

    int* flag = (int*)d_ws;
    float* P  = (float*)d_ws + 16;
    u16* PB   = (u16*)(P + PARAM_SZ);
    u16* h0   = PB + PB_SZ;                    // 2 x 40000*64 bf16 (double buffer)
    u16* h1   = h0 + (size_t)2 * NN * HH;
    float* partial = (float*)(h1 + (size_t)2 * NN * HH);
    int* ioff   = (int*)(partial + 1024);
    int* cursor = ioff + 2 * (NN + 1) + 62;
    int* esrc   = cursor + 2 * NN;

    hipMemsetAsync(ioff, 0, 2 * (NN + 1) * sizeof(int), stream);

    sniff_kernel<<<1, 64, 0, stream>>>((const u16*)d_in[8], flag);
    conv_kernel<<<96, 256, 0, stream>>>(d_in[8], d_in[9], d_in[10], d_in[11], d_in[12], d_in[13],
                                        d_in[14], d_in[15], d_in[16], d_in[17], d_in[18], d_in[19],
                                        P, PB, flag);
    hist_kernel<<<(2 * EE) / 256, 256, 0, stream>>>(adj0, adj1, ioff);
    scan_kernel<<<2, 1024, 0, stream>>>(ioff, cursor);
    scatter_kernel<<<(2 * EE) / 256, 256, 0, stream>>>(adj0, adj1, cursor, esrc);
    projm_kernel<<<(2 * NN) / 64, 256, 0, stream>>>(d_in[7], (const int*)d_in[0],
                                                    (const int*)d_in[1], P, PB, h0, flag);

    u16* hcur = h0;
    u16* hnext = h1;
    for (int l = 0; l < 2; ++l) {
        for (int t = 0; t < 3; ++t) {
            gstep_kernel<<<(2 * NN) / 64, 256, 0, stream>>>(hcur, hnext, ioff, esrc, P, PB, l);
            u16* tmp = hcur; hcur = hnext; hnext = tmp;
        }
    }
    // 6 steps -> final state back in h0 (== hcur)

    cls_kernel<<<BB / 4, 256, 0, stream>>>(hcur, prop0, prop1, labels, P, d_out, partial, flag);
    loss_kernel<<<1, 256, 0, stream>>>(partial, d_out, flag);
}

// Round 7
// 464.773 us; speedup vs baseline: 9.4717x; 1.1762x over previous
//
#include <hip/hip_runtime.h>
#include <hip/hip_bf16.h>

typedef unsigned short u16;
typedef __attribute__((ext_vector_type(8))) short s16x8;   // 8 bf16 MFMA A/B frag
typedef __attribute__((ext_vector_type(4))) float f32x4;   // MFMA C/D frag

#define NN 20000
#define HH 64
#define EMBD 300
#define EE 160000
#define BB 4096
#define NODES 40000
#define SLST  640000   // NODES*16 (u16 units): one feature-slice region

// f32 param block offsets (floats) in workspace (after 16-float header)
#define OFF_PROJB 0
#define OFF_MSGB  64
#define OFF_BIH   192
#define OFF_BHH   576
#define OFF_CW1T  960
#define OFF_CB1   3008
#define OFF_CW2   3024
#define OFF_CB2   3040
#define PARAM_SZ  3072

// bf16 frag-swizzled weight blocks (u16 units). Each "frag" = 512 u16 = one
// 16(row)x32(k) B-tile stored so lane L reads its 8 elements at frag*512+L*8.
#define PB_WIH   0        // 2 l x 24 frags (jt 0..11, kt 0..1)
#define PB_WHH   24576
#define PB_WMT   49152    // 2 l x 8 frags (jt 0..3, kt 0..1)
#define PB_PROJT 57344    // 40 frags (frag = jt*10+kt, jt 0..3, kt 0..9)
#define PB_SZ    77824

// projm LDS A-tile row stride (u16): 344 -> 172 dwords, <=2-way bank alias (free)
#define APAD 344

__device__ __forceinline__ float b2f(u16 u) {
    union { unsigned int i; float f; } v; v.i = ((unsigned int)u) << 16; return v.f;
}
__device__ __forceinline__ u16 f2b(float f) {
    union { float f; unsigned int u; } v; v.f = f;
    unsigned int u = v.u;
    return (u16)((u + 0x7FFFu + ((u >> 16) & 1u)) >> 16);   // RNE
}
__device__ __forceinline__ float ldf(const void* p, long long i, int isbf) {
    return isbf ? b2f(((const u16*)p)[i]) : ((const float*)p)[i];
}
__device__ __forceinline__ u16 ldb(const void* p, long long i, int isbf) {
    return isbf ? ((const u16*)p)[i] : f2b(((const float*)p)[i]);
}
__device__ __forceinline__ void stf(void* p, long long i, int isbf, float v) {
    if (isbf) ((u16*)p)[i] = f2b(v);
    else      ((float*)p)[i] = v;
}

// ---------------- dtype sniffer ----------------
__global__ void sniff_kernel(const u16* probe, int* flag)
{
    if (threadIdx.x == 0 && blockIdx.x == 0) {
        int good = 0;
        for (int i = 0; i < 128; i += 2) {
            unsigned int e = (probe[i] >> 7) & 0xFF;
            if (e >= 105 && e <= 127) good++;
        }
        *flag = (good >= 48) ? 1 : 0;
    }
}

// ---------------- param convert + frag swizzle ----------------
__global__ __launch_bounds__(256) void conv_kernel(
    const void* projW, const void* projb, const void* msgW, const void* msgb,
    const void* wih, const void* whh, const void* bih, const void* bhh,
    const void* cw1, const void* cb1, const void* cw2, const void* cb2,
    float* P, u16* PB, const int* flag)
{
    int isbf = *flag;
    int i = blockIdx.x * 256 + threadIdx.x;
    if (i < 64)    P[OFF_PROJB + i] = ldf(projb, i, isbf);
    if (i < 128)   P[OFF_MSGB + i]  = ldf(msgb, i, isbf);
    if (i < 384)   { P[OFF_BIH + i] = ldf(bih, i, isbf); P[OFF_BHH + i] = ldf(bhh, i, isbf); }
    if (i < 2048)  { int t = i >> 7, k = i & 127; P[OFF_CW1T + i] = ldf(cw1, (long long)k * 16 + t, isbf); }
    if (i < 16)    { P[OFF_CB1 + i] = ldf(cb1, i, isbf); P[OFF_CW2 + i] = ldf(cw2, i, isbf); }
    if (i == 0)    P[OFF_CB2] = ldf(cb2, 0, isbf);

    if (i < 24576) {   // Wih/Whh swizzle: per-l 24 frags
        int l = i / 12288, r = i - l * 12288;
        int frag = r >> 9, rr = r & 511, lane = rr >> 3, e = rr & 7;
        int jt = frag >> 1, kt = frag & 1;
        int srow = jt * 16 + (lane & 15);
        int sk = kt * 32 + ((lane >> 4) << 3) + e;
        long long si = (long long)l * 12288 + srow * 64 + sk;
        PB[PB_WIH + i] = ldb(wih, si, isbf);
        PB[PB_WHH + i] = ldb(whh, si, isbf);
    }
    if (i < 8192) {    // msgW^T swizzle
        int l = i >> 12, r = i & 4095;
        int frag = r >> 9, rr = r & 511, lane = rr >> 3, e = rr & 7;
        int jt = frag >> 1, kt = frag & 1;
        int srow = jt * 16 + (lane & 15);
        int sk = kt * 32 + ((lane >> 4) << 3) + e;
        PB[PB_WMT + i] = ldb(msgW, (long long)l * 4096 + sk * 64 + srow, isbf);
    }
    if (i < 20480) {   // projW^T swizzle, k zero-padded >=300
        int frag = i >> 9, rr = i & 511, lane = rr >> 3, e = rr & 7;
        int jt = frag / 10, kt = frag - jt * 10;
        int srow = jt * 16 + (lane & 15);
        int sk = kt * 32 + ((lane >> 4) << 3) + e;
        PB[PB_PROJT + i] = (sk < 300) ? ldb(projW, (long long)sk * 64 + srow, isbf) : (u16)0;
    }
}

// ---------------- CSR build ----------------
__global__ __launch_bounds__(256) void hist_kernel(const int* __restrict__ adj0,
                                                   const int* __restrict__ adj1, int* off)
{
    int e = blockIdx.x * 256 + threadIdx.x;
    if (e >= 2 * EE) return;
    int b = e / EE, le = e - b * EE;
    const int* adj = b ? adj1 : adj0;
    int tgt = adj[2 * le + 1];
    atomicAdd(&off[b * (NN + 1) + tgt + 1], 1);
}

__global__ __launch_bounds__(1024) void scan_kernel(int* off, int* cursor)
{
    int b = blockIdx.x;
    int* o = off + (size_t)b * (NN + 1);
    int* cur = cursor + (size_t)b * NN;
    __shared__ int wsum[16];
    __shared__ int wscan[16];
    int tid = threadIdx.x, wv = tid >> 6, lane = tid & 63;
    int base = 0;
    for (int start = 0; start < NN; start += 1024) {
        int i = start + tid;
        int v = (i < NN) ? o[i + 1] : 0;
        int orig = v;
        #pragma unroll
        for (int d = 1; d < 64; d <<= 1) {
            int t = __shfl_up(v, d);
            if (lane >= d) v += t;
        }
        if (lane == 63) wsum[wv] = v;
        __syncthreads();
        if (tid < 16) {
            int w = wsum[tid];
            #pragma unroll
            for (int d = 1; d < 16; d <<= 1) {
                int t = __shfl_up(w, d, 16);
                if (tid >= d) w += t;
            }
            wscan[tid] = w;
        }
        __syncthreads();
        int woff = (wv == 0) ? 0 : wscan[wv - 1];
        int excl = base + woff + v - orig;
        if (i < NN) { o[i] = excl; cur[i] = excl; }
        base += wscan[15];
    }
    if (tid == 0) o[NN] = base;
}

__global__ __launch_bounds__(256) void scatter_kernel(const int* __restrict__ adj0,
                                                      const int* __restrict__ adj1,
                                                      int* cursor, int* esrc)
{
    int e = blockIdx.x * 256 + threadIdx.x;
    if (e >= 2 * EE) return;
    int b = e / EE, le = e - b * EE;
    const int* adj = b ? adj1 : adj0;
    int src = adj[2 * le + 0];
    int tgt = adj[2 * le + 1];
    int pos = atomicAdd(&cursor[b * NN + tgt], 1);
    esrc[(size_t)b * EE + pos] = src;
}

// ---------------- embedding gather + projection (MFMA), sliced h output -----
__global__ __launch_bounds__(256) void projm_kernel(const void* emb,
                                                    const int* __restrict__ i0,
                                                    const int* __restrict__ i1,
                                                    const float* __restrict__ P,
                                                    const u16* __restrict__ PB,
                                                    u16* __restrict__ h, const int* flag)
{
    __shared__ u16 sA[64 * APAD];
    int isbf = *flag;
    int tid = threadIdx.x;
    int node0 = blockIdx.x * 64;

    // stage 64 embedding rows, 4 threads per row (wave w stages+reads rows 16w..16w+15)
    {
        int r = tid >> 2, sub = tid & 3;
        int n = node0 + r;
        int b = n >= NN;
        int ln = n - b * NN;
        int idx = b ? i1[ln] : i0[ln];
        if (isbf) {
            const ushort4* src = (const ushort4*)((const u16*)emb + (size_t)idx * EMBD);
            ushort4* dst = (ushort4*)(sA + r * APAD);
            for (int c = sub; c < 75; c += 4) dst[c] = src[c];
            if (sub == 0) {
                ushort4 z = {0, 0, 0, 0};
                for (int c = 75; c < 80; ++c) dst[c] = z;
            }
        } else {
            const float* src = (const float*)emb + (size_t)idx * EMBD;
            for (int k = sub; k < 300; k += 4) sA[r * APAD + k] = f2b(src[k]);
            if (sub == 0) for (int k = 300; k < 320; ++k) sA[r * APAD + k] = 0;
        }
    }

    int wv = tid >> 6, lane = tid & 63, quad = lane >> 4, cn = lane & 15;
    int m0 = wv * 16;
    f32x4 acc[4];
    #pragma unroll
    for (int j = 0; j < 4; ++j) {
        float bb = P[OFF_PROJB + j * 16 + cn];
        acc[j] = {bb, bb, bb, bb};
    }
    #pragma unroll
    for (int kt = 0; kt < 10; ++kt) {
        s16x8 a = *(const s16x8*)&sA[(m0 + cn) * APAD + kt * 32 + quad * 8];
        #pragma unroll
        for (int j = 0; j < 4; ++j) {
            s16x8 bfr = *(const s16x8*)&PB[PB_PROJT + (j * 10 + kt) * 512 + lane * 8];
            acc[j] = __builtin_amdgcn_mfma_f32_16x16x32_bf16(a, bfr, acc[j], 0, 0, 0);
        }
    }
    #pragma unroll
    for (int j = 0; j < 4; ++j)
        #pragma unroll
        for (int r = 0; r < 4; ++r)
            h[(size_t)j * SLST + (size_t)(node0 + m0 + quad * 4 + r) * 16 + cn] = f2b(acc[j][r]);
}

// ---------------- neighbor gather-sum, XCD-sliced -----------------------------
// grid = 4 slices x 2500 node-tiles; slice = blockIdx&3 so (round-robin XCD
// dispatch) slice s lands on XCDs {s, s+4}: per-XCD working set = 1.28 MB slice
// region -> L2-resident. Thread = (node in tile, feat): 16-lane groups read
// 32-B granules.
__global__ __launch_bounds__(256) void gatherS_kernel(const u16* __restrict__ h_old,
                                                      u16* __restrict__ Sbuf,
                                                      const int* __restrict__ ioff,
                                                      const int* __restrict__ esrc)
{
    int b = blockIdx.x;
    int slice = b & 3;
    int tile = b >> 2;                 // 0..2499
    int tid = threadIdx.x;
    int i = tid >> 4, feat = tid & 15;
    int node = tile * 16 + i;          // 0..39999 exact
    int br = node >= NN;
    int ln = node - br * NN;
    const int* o = ioff + (size_t)br * (NN + 1);
    int s0 = o[ln], s1 = o[ln + 1];
    const int* es = esrc + (size_t)br * EE;
    const u16* hb = h_old + (size_t)slice * SLST + (size_t)br * NN * 16;
    float a0 = 0.f, a1 = 0.f, a2 = 0.f, a3 = 0.f;
    int e = s0;
    for (; e + 4 <= s1; e += 4) {
        int e0 = es[e], e1 = es[e + 1], e2 = es[e + 2], e3 = es[e + 3];
        a0 += b2f(hb[(size_t)e0 * 16 + feat]);
        a1 += b2f(hb[(size_t)e1 * 16 + feat]);
        a2 += b2f(hb[(size_t)e2 * 16 + feat]);
        a3 += b2f(hb[(size_t)e3 * 16 + feat]);
    }
    for (; e < s1; ++e) a0 += b2f(hb[(size_t)es[e] * 16 + feat]);
    Sbuf[(size_t)slice * SLST + (size_t)node * 16 + feat] = f2b(a0 + a1 + a2 + a3);
}

// ---------------- GRU step (MFMA, pure compute; sliced S/h I/O) --------------
__global__ __launch_bounds__(256) void gstep_kernel(const u16* __restrict__ Sbuf,
                                                    const u16* __restrict__ h_old,
                                                    u16* __restrict__ h_new,
                                                    const int* __restrict__ ioff,
                                                    const float* __restrict__ P,
                                                    const u16* __restrict__ PB, int l)
{
    __shared__ u16 s_S[4096];
    __shared__ u16 s_h[4096];
    __shared__ float s_deg[64];

    int tid = threadIdx.x;
    int wv = tid >> 6, lane = tid & 63;
    int node0 = blockIdx.x * 64;
    int m0 = wv * 16;

    // stage own rows (wave-private) from sliced layout into node-major LDS
    #pragma unroll
    for (int it = 0; it < 2; ++it) {
        int idx = it * 64 + lane;      // 0..127 = slice(4) x nodelo(16) x half(2)
        int slice = idx >> 5;
        int rem = idx & 31;
        int nlo = rem >> 1, half = rem & 1;
        int row = m0 + nlo;
        size_t goff = (size_t)slice * SLST + (size_t)(node0 + row) * 16 + half * 8;
        *(uint4*)(s_h + row * 64 + slice * 16 + half * 8) = *(const uint4*)(h_old + goff);
        *(uint4*)(s_S + row * 64 + slice * 16 + half * 8) = *(const uint4*)(Sbuf + goff);
    }
    if (lane < 16) {
        int row = m0 + lane;
        int n = node0 + row;
        int br = n >= NN;
        int ln = n - br * NN;
        const int* o = ioff + (size_t)br * (NN + 1);
        s_deg[row] = (float)(o[ln + 1] - o[ln]);
    }

    int quad = lane >> 4, cn = lane & 15;
    int arow = (m0 + cn) * 64 + quad * 8;
    int fl = lane * 8;

    // phase 1: inc = S @ msgW + deg*msgb (wave-private rows, alias-safe)
    s16x8 aS0 = *(const s16x8*)&s_S[arow];
    s16x8 aS1 = *(const s16x8*)&s_S[arow + 32];
    const u16* WM = PB + PB_WMT + (size_t)l * 4096;
    #pragma unroll
    for (int jt = 0; jt < 4; ++jt) {
        float mb = P[OFF_MSGB + l * 64 + jt * 16 + cn];
        f32x4 acc;
        acc[0] = s_deg[m0 + quad * 4 + 0] * mb;
        acc[1] = s_deg[m0 + quad * 4 + 1] * mb;
        acc[2] = s_deg[m0 + quad * 4 + 2] * mb;
        acc[3] = s_deg[m0 + quad * 4 + 3] * mb;
        acc = __builtin_amdgcn_mfma_f32_16x16x32_bf16(aS0, *(const s16x8*)&WM[(jt * 2 + 0) * 512 + fl], acc, 0, 0, 0);
        acc = __builtin_amdgcn_mfma_f32_16x16x32_bf16(aS1, *(const s16x8*)&WM[(jt * 2 + 1) * 512 + fl], acc, 0, 0, 0);
        #pragma unroll
        for (int r = 0; r < 4; ++r)
            s_S[(m0 + quad * 4 + r) * 64 + jt * 16 + cn] = f2b(acc[r]);
    }

    // phase 2+3: gi/gh GEMMs (B-frags coalesced from global) + fused GRU
    s16x8 aI0 = *(const s16x8*)&s_S[arow];
    s16x8 aI1 = *(const s16x8*)&s_S[arow + 32];
    s16x8 aH0 = *(const s16x8*)&s_h[arow];
    s16x8 aH1 = *(const s16x8*)&s_h[arow + 32];
    const u16* WI = PB + PB_WIH + (size_t)l * 12288;
    const u16* WH = PB + PB_WHH + (size_t)l * 12288;
    const float* bi = P + OFF_BIH + l * 192;
    const float* bh = P + OFF_BHH + l * 192;

    #pragma unroll
    for (int c = 0; c < 4; ++c) {
        int j0 = c * 16;
        float vr = bi[j0 + cn], vz = bi[64 + j0 + cn], vn = bi[128 + j0 + cn];
        float wr = bh[j0 + cn], wz = bh[64 + j0 + cn], wn = bh[128 + j0 + cn];
        f32x4 gr = {vr, vr, vr, vr}, gz = {vz, vz, vz, vz}, gn = {vn, vn, vn, vn};
        f32x4 hr = {wr, wr, wr, wr}, hz = {wz, wz, wz, wz}, hn = {wn, wn, wn, wn};
        int fr = (c * 2) * 512 + fl, frz = ((4 + c) * 2) * 512 + fl, frn = ((8 + c) * 2) * 512 + fl;
        gr = __builtin_amdgcn_mfma_f32_16x16x32_bf16(aI0, *(const s16x8*)&WI[fr], gr, 0, 0, 0);
        gr = __builtin_amdgcn_mfma_f32_16x16x32_bf16(aI1, *(const s16x8*)&WI[fr + 512], gr, 0, 0, 0);
        gz = __builtin_amdgcn_mfma_f32_16x16x32_bf16(aI0, *(const s16x8*)&WI[frz], gz, 0, 0, 0);
        gz = __builtin_amdgcn_mfma_f32_16x16x32_bf16(aI1, *(const s16x8*)&WI[frz + 512], gz, 0, 0, 0);
        gn = __builtin_amdgcn_mfma_f32_16x16x32_bf16(aI0, *(const s16x8*)&WI[frn], gn, 0, 0, 0);
        gn = __builtin_amdgcn_mfma_f32_16x16x32_bf16(aI1, *(const s16x8*)&WI[frn + 512], gn, 0, 0, 0);
        hr = __builtin_amdgcn_mfma_f32_16x16x32_bf16(aH0, *(const s16x8*)&WH[fr], hr, 0, 0, 0);
        hr = __builtin_amdgcn_mfma_f32_16x16x32_bf16(aH1, *(const s16x8*)&WH[fr + 512], hr, 0, 0, 0);
        hz = __builtin_amdgcn_mfma_f32_16x16x32_bf16(aH0, *(const s16x8*)&WH[frz], hz, 0, 0, 0);
        hz = __builtin_amdgcn_mfma_f32_16x16x32_bf16(aH1, *(const s16x8*)&WH[frz + 512], hz, 0, 0, 0);
        hn = __builtin_amdgcn_mfma_f32_16x16x32_bf16(aH0, *(const s16x8*)&WH[frn], hn, 0, 0, 0);
        hn = __builtin_amdgcn_mfma_f32_16x16x32_bf16(aH1, *(const s16x8*)&WH[frn + 512], hn, 0, 0, 0);
        #pragma unroll
        for (int r = 0; r < 4; ++r) {
            int row = m0 + quad * 4 + r;
            float rr = 1.f / (1.f + __expf(-(gr[r] + hr[r])));
            float zz = 1.f / (1.f + __expf(-(gz[r] + hz[r])));
            float nn = tanhf(gn[r] + rr * hn[r]);
            float ho = b2f(s_h[row * 64 + j0 + cn]);
            h_new[(size_t)c * SLST + (size_t)(node0 + row) * 16 + cn] = f2b((1.f - zz) * nn + zz * ho);
        }
    }
}

// ---------------- classifier: wave-per-sample (sliced h reads) ----------------
__global__ __launch_bounds__(256) void cls_kernel(const u16* __restrict__ h,
                                                  const int* __restrict__ p0,
                                                  const int* __restrict__ p1,
                                                  const int* __restrict__ labels,
                                                  const float* __restrict__ P,
                                                  void* out, float* partial, const int* flag)
{
    int isbf = *flag;
    int wv = threadIdx.x >> 6, lane = threadIdx.x & 63;
    int s = blockIdx.x * 4 + wv;               // 1024 blocks x 4 waves = 4096
    int n0 = p0[s], n1 = p1[s];
    size_t sl = (size_t)(lane >> 4) * SLST;
    float f0 = b2f(h[sl + (size_t)n0 * 16 + (lane & 15)]);
    float f1 = b2f(h[sl + (size_t)(NN + n1) * 16 + (lane & 15)]);
    float z = P[OFF_CB2];
    #pragma unroll
    for (int t = 0; t < 16; ++t) {
        float part = f0 * P[OFF_CW1T + t * 128 + lane] + f1 * P[OFF_CW1T + t * 128 + 64 + lane];
        #pragma unroll
        for (int off = 32; off; off >>= 1) part += __shfl_xor(part, off);
        z += fmaxf(part + P[OFF_CB1 + t], 0.f) * P[OFF_CW2 + t];
    }
    float p = 1.f / (1.f + expf(-z));
    float y = (float)labels[s];
    const float eps = 1e-7f;
    float pc  = fminf(fmaxf(p, eps), 1.f);
    float pc1 = fminf(fmaxf(1.f - p, eps), 1.f);
    float term = y * logf(pc) + (1.f - y) * logf(pc1);
    __shared__ float red[4];
    if (lane == 0) { stf(out, s, isbf, p); red[wv] = term; }
    __syncthreads();
    if (threadIdx.x == 0) partial[blockIdx.x] = red[0] + red[1] + red[2] + red[3];
}

__global__ __launch_bounds__(256) void loss_kernel(const float* __restrict__ partial,
                                                   void* out, const int* flag)
{
    __shared__ float red[256];
    int tid = threadIdx.x;
    float s = 0.f;
    for (int i = tid; i < 1024; i += 256) s += partial[i];
    red[tid] = s;
    __syncthreads();
    for (int d = 128; d > 0; d >>= 1) {
        if (tid < d) red[tid] += red[tid + d];
        __syncthreads();
    }
    if (tid == 0) stf(out, BB, *flag, -red[0] / (float)BB);
}

extern "C" void kernel_launch(void* const* d_in, const int* in_sizes, int n_in,
                              void* d_out, int out_size, void* d_ws, size_t ws_size,
                              hipStream_t stream)
{
    const int* adj0   = (const int*)d_in[2];
    const int* adj1   = (const int*)d_in[3];
    const int* prop0  = (const int*)d_in[4];
    const int* prop1  = (const int*)d_in[5];
    const int* labels = (const int*)d_in[6];

    int* flag = (int*)d_ws;
    float* P  = (float*)d_ws + 16;
    u16* PB   = (u16*)(P + PARAM_SZ);
    u16* h0   = PB + PB_SZ;                    // sliced: 4 x 40000 x 16 bf16
    u16* h1   = h0 + (size_t)4 * SLST / 4 * 4; // = h0 + 2560000
    u16* SB   = h1 + (size_t)2560000;
    float* partial = (float*)(SB + (size_t)2560000);
    int* ioff   = (int*)(partial + 1024);
    int* cursor = ioff + 2 * (NN + 1) + 62;
    int* esrc   = cursor + 2 * NN;

    hipMemsetAsync(ioff, 0, 2 * (NN + 1) * sizeof(int), stream);

    sniff_kernel<<<1, 64, 0, stream>>>((const u16*)d_in[8], flag);
    conv_kernel<<<96, 256, 0, stream>>>(d_in[8], d_in[9], d_in[10], d_in[11], d_in[12], d_in[13],
                                        d_in[14], d_in[15], d_in[16], d_in[17], d_in[18], d_in[19],
                                        P, PB, flag);
    hist_kernel<<<(2 * EE) / 256, 256, 0, stream>>>(adj0, adj1, ioff);
    scan_kernel<<<2, 1024, 0, stream>>>(ioff, cursor);
    scatter_kernel<<<(2 * EE) / 256, 256, 0, stream>>>(adj0, adj1, cursor, esrc);
    projm_kernel<<<(2 * NN) / 64, 256, 0, stream>>>(d_in[7], (const int*)d_in[0],
                                                    (const int*)d_in[1], P, PB, h0, flag);

    u16* hcur = h0;
    u16* hnext = h1;
    for (int l = 0; l < 2; ++l) {
        for (int t = 0; t < 3; ++t) {
            gatherS_kernel<<<4 * (NODES / 16), 256, 0, stream>>>(hcur, SB, ioff, esrc);
            gstep_kernel<<<NODES / 64, 256, 0, stream>>>(SB, hcur, hnext, ioff, P, PB, l);
            u16* tmp = hcur; hcur = hnext; hnext = tmp;
        }
    }
    // 6 steps -> final state back in h0 (== hcur)

    cls_kernel<<<BB / 4, 256, 0, stream>>>(hcur, prop0, prop1, labels, P, d_out, partial, flag);
    loss_kernel<<<1, 256, 0, stream>>>(partial, d_out, flag);
}